// Round 1
// baseline (714.496 us; speedup 1.0000x reference)
//
#include <hip/hip_runtime.h>

// GResNet GCN: N=50000 nodes, E=800000 edges, d_in=128, d_hid=128, d_out=64.
// Strategy: build dst-CSR once per call, aggregates as gather-sum (1 wave/node),
// fp32 VALU GEMM with W in LDS. res computed once (identical for both blocks).
// Final layer: GEMM before aggregate (64-wide aggregate, half traffic).

#define GN 50000
#define GE 800000

__global__ void degrees_kernel(const int* __restrict__ src, const int* __restrict__ dst,
                               int* __restrict__ indeg, int* __restrict__ outdeg, int E) {
  int e = blockIdx.x * blockDim.x + threadIdx.x;
  if (e < E) {
    atomicAdd(&indeg[dst[e]], 1);
    atomicAdd(&outdeg[src[e]], 1);
  }
}

__global__ void norms_kernel(const int* __restrict__ indeg, const int* __restrict__ outdeg,
                             float* __restrict__ innorm, float* __restrict__ outnorm, int n) {
  int i = blockIdx.x * blockDim.x + threadIdx.x;
  if (i < n) {
    innorm[i]  = rsqrtf((float)max(indeg[i], 1));
    outnorm[i] = rsqrtf((float)max(outdeg[i], 1));
  }
}

// Single-block exclusive scan over indeg -> offsets (and cursor copy).
__global__ void scan_kernel(const int* __restrict__ deg, int* __restrict__ offsets,
                            int* __restrict__ cursor, int n) {
  __shared__ int sm[1024];
  __shared__ int carry_s;
  if (threadIdx.x == 0) carry_s = 0;
  __syncthreads();
  for (int base = 0; base < n; base += 1024) {
    int i = base + threadIdx.x;
    int v = (i < n) ? deg[i] : 0;
    sm[threadIdx.x] = v;
    __syncthreads();
    for (int off = 1; off < 1024; off <<= 1) {
      int t = (threadIdx.x >= off) ? sm[threadIdx.x - off] : 0;
      __syncthreads();
      sm[threadIdx.x] += t;
      __syncthreads();
    }
    int excl = carry_s + sm[threadIdx.x] - v;
    if (i < n) { offsets[i] = excl; cursor[i] = excl; }
    __syncthreads();
    if (threadIdx.x == 0) carry_s += sm[1023];
    __syncthreads();
  }
  if (threadIdx.x == 0) offsets[n] = carry_s;
}

__global__ void fill_csr_kernel(const int* __restrict__ src, const int* __restrict__ dst,
                                int* __restrict__ cursor, int* __restrict__ csr, int E) {
  int e = blockIdx.x * blockDim.x + threadIdx.x;
  if (e < E) {
    int pos = atomicAdd(&cursor[dst[e]], 1);
    csr[pos] = src[e];
  }
}

// out[node] = wscale[node] * sum_{e in in(node)} gscale[src_e] * h[src_e]  (+ bias)
// One wave per node. D=128: 32 lanes cover a row (float4), 2 edges in parallel.
// D=64: 16 lanes cover a row, 4 edges in parallel.
template <int D, bool ADD_BIAS>
__global__ __launch_bounds__(256) void aggregate_kernel(
    const float* __restrict__ h, const float* __restrict__ gscale,
    const float* __restrict__ wscale, const float* __restrict__ bias,
    const int* __restrict__ offsets, const int* __restrict__ csr,
    float* __restrict__ out, int n) {
  constexpr int LPR = D / 4;       // lanes per row
  constexpr int EPW = 64 / LPR;    // edges in parallel per wave
  int node = blockIdx.x * 4 + (threadIdx.x >> 6);
  if (node >= n) return;
  int lane = threadIdx.x & 63;
  int c = lane % LPR;
  int p = lane / LPR;
  int s = offsets[node], e = offsets[node + 1];
  float4 acc = make_float4(0.f, 0.f, 0.f, 0.f);
  for (int i = s + p; i < e; i += EPW) {
    int sn = csr[i];
    float sc = gscale[sn];
    float4 v = *((const float4*)(h + (size_t)sn * D) + c);
    acc.x += v.x * sc; acc.y += v.y * sc; acc.z += v.z * sc; acc.w += v.w * sc;
  }
#pragma unroll
  for (int off = 32; off >= LPR; off >>= 1) {
    acc.x += __shfl_down(acc.x, off);
    acc.y += __shfl_down(acc.y, off);
    acc.z += __shfl_down(acc.z, off);
    acc.w += __shfl_down(acc.w, off);
  }
  if (lane < LPR) {
    float wsc = wscale[node];
    float4 o;
    o.x = acc.x * wsc; o.y = acc.y * wsc; o.z = acc.z * wsc; o.w = acc.w * wsc;
    if (ADD_BIAS) {
      float4 b = ((const float4*)bias)[c];
      o.x += b.x; o.y += b.y; o.z += b.z; o.w += b.w;
    }
    *((float4*)(out + (size_t)node * D) + c) = o;
  }
}

// out(n x DOUT) = A(n x 128) @ W(128 x DOUT) [+ bias] [+ res] [relu]
// W staged fully in LDS; 32-row tiles; each thread computes RPT rows x 4 cols.
template <int DOUT, bool RELU, bool HAS_BIAS, bool ADD_RES>
__global__ __launch_bounds__(256) void gemm_kernel(
    const float* __restrict__ A, const float* __restrict__ W,
    const float* __restrict__ bias, const float* __restrict__ res,
    float* __restrict__ out, int n) {
  __shared__ float Wl[128 * DOUT];
  __shared__ float Al[32 * 128];
  for (int i = threadIdx.x; i < 128 * DOUT / 4; i += 256)
    ((float4*)Wl)[i] = ((const float4*)W)[i];
  int row0 = blockIdx.x * 32;
  for (int i = threadIdx.x; i < 32 * 32; i += 256) {
    int r = i >> 5, cc = i & 31;
    int gr = row0 + r;
    float4 v = make_float4(0.f, 0.f, 0.f, 0.f);
    if (gr < n) v = *((const float4*)(A + (size_t)gr * 128) + cc);
    *((float4*)(Al + r * 128) + cc) = v;
  }
  __syncthreads();
  constexpr int CG = DOUT / 4;     // col groups (float4)
  constexpr int RG = 256 / CG;     // row groups
  constexpr int RPT = 32 / RG;     // rows per thread
  int tc = threadIdx.x % CG;
  int tr = threadIdx.x / CG;
  float4 acc[RPT];
#pragma unroll
  for (int r = 0; r < RPT; r++) acc[r] = make_float4(0.f, 0.f, 0.f, 0.f);
  for (int k = 0; k < 128; k++) {
    float4 w = *((const float4*)(Wl + k * DOUT) + tc);
#pragma unroll
    for (int r = 0; r < RPT; r++) {
      float a = Al[(tr * RPT + r) * 128 + k];
      acc[r].x += a * w.x; acc[r].y += a * w.y;
      acc[r].z += a * w.z; acc[r].w += a * w.w;
    }
  }
  float4 b = make_float4(0.f, 0.f, 0.f, 0.f);
  if (HAS_BIAS) b = ((const float4*)bias)[tc];
#pragma unroll
  for (int r = 0; r < RPT; r++) {
    int gr = row0 + tr * RPT + r;
    if (gr < n) {
      float4 o = acc[r];
      o.x += b.x; o.y += b.y; o.z += b.z; o.w += b.w;
      if (ADD_RES) {
        float4 rr = *((const float4*)(res + (size_t)gr * DOUT) + tc);
        o.x += rr.x; o.y += rr.y; o.z += rr.z; o.w += rr.w;
      }
      if (RELU) {
        o.x = fmaxf(o.x, 0.f); o.y = fmaxf(o.y, 0.f);
        o.z = fmaxf(o.z, 0.f); o.w = fmaxf(o.w, 0.f);
      }
      *((float4*)(out + (size_t)gr * DOUT) + tc) = o;
    }
  }
}

extern "C" void kernel_launch(void* const* d_in, const int* in_sizes, int n_in,
                              void* d_out, int out_size, void* d_ws, size_t ws_size,
                              hipStream_t stream) {
  const float* features = (const float*)d_in[0];
  const int*   src      = (const int*)d_in[1];
  const int*   dst      = (const int*)d_in[2];
  const float* W0 = (const float*)d_in[3];
  const float* b0 = (const float*)d_in[4];
  const float* W1 = (const float*)d_in[5];
  const float* b1 = (const float*)d_in[6];
  const float* W2 = (const float*)d_in[7];
  const float* b2 = (const float*)d_in[8];
  const float* W3 = (const float*)d_in[9];
  const float* b3 = (const float*)d_in[10];
  float* out = (float*)d_out;
  const int N = GN, E = GE;

  char* ws = (char*)d_ws;
  size_t off = 0;
  auto alloc = [&](size_t bytes) -> void* {
    void* p = ws + off;
    off = (off + bytes + 255) & ~(size_t)255;
    return p;
  };
  int*   indeg   = (int*)alloc((size_t)N * 4);
  int*   outdeg  = (int*)alloc((size_t)N * 4);
  float* innorm  = (float*)alloc((size_t)N * 4);
  float* outnorm = (float*)alloc((size_t)N * 4);
  int*   offsets = (int*)alloc((size_t)(N + 1) * 4);
  int*   cursor  = (int*)alloc((size_t)N * 4);
  int*   csr     = (int*)alloc((size_t)E * 4);
  float* res     = (float*)alloc((size_t)N * 128 * 4);
  float* bufA    = (float*)alloc((size_t)N * 128 * 4);
  float* bufB    = (float*)alloc((size_t)N * 128 * 4);
  float* Y       = (float*)alloc((size_t)N * 64 * 4);
  (void)ws_size; (void)in_sizes; (void)n_in; (void)out_size;

  hipMemsetAsync(indeg, 0, (size_t)N * 4, stream);
  hipMemsetAsync(outdeg, 0, (size_t)N * 4, stream);

  degrees_kernel<<<(E + 255) / 256, 256, 0, stream>>>(src, dst, indeg, outdeg, E);
  norms_kernel<<<(N + 255) / 256, 256, 0, stream>>>(indeg, outdeg, innorm, outnorm, N);
  scan_kernel<<<1, 1024, 0, stream>>>(indeg, offsets, cursor, N);
  fill_csr_kernel<<<(E + 255) / 256, 256, 0, stream>>>(src, dst, cursor, csr, E);

  int aggGrid  = (N + 3) / 4;
  int gemmGrid = (N + 31) / 32;

  // t0 = innorm .* agg(outnorm .* features)
  aggregate_kernel<128, false><<<aggGrid, 256, 0, stream>>>(
      features, outnorm, innorm, nullptr, offsets, csr, bufA, N);
  // res = innorm .* agg(innorm .* features)   (shared by both GResConv blocks)
  aggregate_kernel<128, false><<<aggGrid, 256, 0, stream>>>(
      features, innorm, innorm, nullptr, offsets, csr, res, N);
  // h0 = relu(t0 @ W0 + b0)
  gemm_kernel<128, true, true, false><<<gemmGrid, 256, 0, stream>>>(
      bufA, W0, b0, nullptr, bufB, N);
  // t1 = innorm .* agg(outnorm .* h0)
  aggregate_kernel<128, false><<<aggGrid, 256, 0, stream>>>(
      bufB, outnorm, innorm, nullptr, offsets, csr, bufA, N);
  // h1 = relu(t1 @ W1 + b1 + res)
  gemm_kernel<128, true, true, true><<<gemmGrid, 256, 0, stream>>>(
      bufA, W1, b1, res, bufB, N);
  // t2 = innorm .* agg(outnorm .* h1)
  aggregate_kernel<128, false><<<aggGrid, 256, 0, stream>>>(
      bufB, outnorm, innorm, nullptr, offsets, csr, bufA, N);
  // h2 = relu(t2 @ W2 + b2 + res)
  gemm_kernel<128, true, true, true><<<gemmGrid, 256, 0, stream>>>(
      bufA, W2, b2, res, bufB, N);
  // Y = h2 @ W3  (matmul commutes with aggregation/diag-scaling; 64-wide saves traffic)
  gemm_kernel<64, false, false, false><<<gemmGrid, 256, 0, stream>>>(
      bufB, W3, nullptr, nullptr, Y, N);
  // out = innorm .* agg(outnorm .* Y) + b3
  aggregate_kernel<64, true><<<aggGrid, 256, 0, stream>>>(
      Y, outnorm, innorm, b3, offsets, csr, out, N);
}

// Round 2
// 572.767 us; speedup vs baseline: 1.2474x; 1.2474x over previous
//
#include <hip/hip_runtime.h>

// GResNet GCN: N=50000, E=800000, d=128 (out 64).
// R1 changes: (1) hierarchical scan (was 92us single-block), (2) fused dual
// aggregate for t0+res (one gather pass instead of two), (3) GEMM k-unroll x4.

#define GN 50000
#define GE 800000
#define SCAN_CHUNK 1024

__global__ void degrees_kernel(const int* __restrict__ src, const int* __restrict__ dst,
                               int* __restrict__ indeg, int* __restrict__ outdeg, int E) {
  int e = blockIdx.x * blockDim.x + threadIdx.x;
  if (e < E) {
    atomicAdd(&indeg[dst[e]], 1);
    atomicAdd(&outdeg[src[e]], 1);
  }
}

__global__ void norms_kernel(const int* __restrict__ indeg, const int* __restrict__ outdeg,
                             float* __restrict__ innorm, float* __restrict__ outnorm, int n) {
  int i = blockIdx.x * blockDim.x + threadIdx.x;
  if (i < n) {
    innorm[i]  = rsqrtf((float)max(indeg[i], 1));
    outnorm[i] = rsqrtf((float)max(outdeg[i], 1));
  }
}

// ---- hierarchical scan: per-chunk sums -> 1-wave scan -> per-chunk scan ----
__global__ __launch_bounds__(256) void scan_blocksums(const int* __restrict__ deg,
                                                      int* __restrict__ bsums, int n) {
  int tid = threadIdx.x;
  int i = blockIdx.x * SCAN_CHUNK + tid * 4;
  int s = 0;
  if (i + 3 < n) {
    int4 v = *(const int4*)(deg + i);
    s = v.x + v.y + v.z + v.w;
  } else {
    for (int j = 0; j < 4; j++) if (i + j < n) s += deg[i + j];
  }
  for (int off = 32; off; off >>= 1) s += __shfl_down(s, off);
  __shared__ int ws[4];
  if ((tid & 63) == 0) ws[tid >> 6] = s;
  __syncthreads();
  if (tid == 0) bsums[blockIdx.x] = ws[0] + ws[1] + ws[2] + ws[3];
}

// nb <= 64: one wave scans the chunk sums; also writes offsets[n] = total.
__global__ void scan_bsums(const int* __restrict__ bsums, int* __restrict__ bpref,
                           int nb, int* __restrict__ offsets, int n) {
  int tid = threadIdx.x;
  int v = (tid < nb) ? bsums[tid] : 0;
  int incl = v;
  for (int off = 1; off < 64; off <<= 1) {
    int t = __shfl_up(incl, off);
    if (tid >= off) incl += t;
  }
  if (tid < nb) bpref[tid] = incl - v;
  if (tid == 63) offsets[n] = incl;
}

__global__ __launch_bounds__(256) void scan_final(const int* __restrict__ deg,
                                                  const int* __restrict__ bpref,
                                                  int* __restrict__ offsets,
                                                  int* __restrict__ cursor, int n) {
  int tid = threadIdx.x;
  int i = blockIdx.x * SCAN_CHUNK + tid * 4;
  int v[4];
#pragma unroll
  for (int j = 0; j < 4; j++) v[j] = (i + j < n) ? deg[i + j] : 0;
  int tsum = v[0] + v[1] + v[2] + v[3];
  int incl = tsum;
  for (int off = 1; off < 64; off <<= 1) {
    int t = __shfl_up(incl, off);
    if ((tid & 63) >= off) incl += t;
  }
  __shared__ int wsum[4];
  int wid = tid >> 6, lane = tid & 63;
  if (lane == 63) wsum[wid] = incl;
  __syncthreads();
  int wpref = 0;
  for (int w = 0; w < wid; w++) wpref += wsum[w];
  int run = bpref[blockIdx.x] + wpref + incl - tsum;
#pragma unroll
  for (int j = 0; j < 4; j++) {
    if (i + j < n) { offsets[i + j] = run; cursor[i + j] = run; }
    run += v[j];
  }
}

__global__ void fill_csr_kernel(const int* __restrict__ src, const int* __restrict__ dst,
                                int* __restrict__ cursor, int* __restrict__ csr, int E) {
  int e = blockIdx.x * blockDim.x + threadIdx.x;
  if (e < E) {
    int pos = atomicAdd(&cursor[dst[e]], 1);
    csr[pos] = src[e];
  }
}

// out[node] = wscale[node] * sum_{e in in(node)} gscale[src_e] * h[src_e]  (+ bias)
template <int D, bool ADD_BIAS>
__global__ __launch_bounds__(256) void aggregate_kernel(
    const float* __restrict__ h, const float* __restrict__ gscale,
    const float* __restrict__ wscale, const float* __restrict__ bias,
    const int* __restrict__ offsets, const int* __restrict__ csr,
    float* __restrict__ out, int n) {
  constexpr int LPR = D / 4;
  constexpr int EPW = 64 / LPR;
  int node = blockIdx.x * 4 + (threadIdx.x >> 6);
  if (node >= n) return;
  int lane = threadIdx.x & 63;
  int c = lane % LPR;
  int p = lane / LPR;
  int s = offsets[node], e = offsets[node + 1];
  float4 acc = make_float4(0.f, 0.f, 0.f, 0.f);
  for (int i = s + p; i < e; i += EPW) {
    int sn = csr[i];
    float sc = gscale[sn];
    float4 v = *((const float4*)(h + (size_t)sn * D) + c);
    acc.x += v.x * sc; acc.y += v.y * sc; acc.z += v.z * sc; acc.w += v.w * sc;
  }
#pragma unroll
  for (int off = 32; off >= LPR; off >>= 1) {
    acc.x += __shfl_down(acc.x, off);
    acc.y += __shfl_down(acc.y, off);
    acc.z += __shfl_down(acc.z, off);
    acc.w += __shfl_down(acc.w, off);
  }
  if (lane < LPR) {
    float wsc = wscale[node];
    float4 o;
    o.x = acc.x * wsc; o.y = acc.y * wsc; o.z = acc.z * wsc; o.w = acc.w * wsc;
    if (ADD_BIAS) {
      float4 b = ((const float4*)bias)[c];
      o.x += b.x; o.y += b.y; o.z += b.z; o.w += b.w;
    }
    *((float4*)(out + (size_t)node * D) + c) = o;
  }
}

// Fused: out1 = w.*agg(g1.*h), out2 = w.*agg(g2.*h) in ONE gather pass (D=128).
__global__ __launch_bounds__(256) void aggregate_dual_kernel(
    const float* __restrict__ h, const float* __restrict__ g1,
    const float* __restrict__ g2, const float* __restrict__ wscale,
    const int* __restrict__ offsets, const int* __restrict__ csr,
    float* __restrict__ out1, float* __restrict__ out2, int n) {
  int node = blockIdx.x * 4 + (threadIdx.x >> 6);
  if (node >= n) return;
  int lane = threadIdx.x & 63;
  int c = lane & 31;
  int p = lane >> 5;
  int s = offsets[node], e = offsets[node + 1];
  float4 a1 = make_float4(0.f, 0.f, 0.f, 0.f);
  float4 a2 = make_float4(0.f, 0.f, 0.f, 0.f);
  for (int i = s + p; i < e; i += 2) {
    int sn = csr[i];
    float s1 = g1[sn], s2 = g2[sn];
    float4 v = *((const float4*)(h + (size_t)sn * 128) + c);
    a1.x += v.x * s1; a1.y += v.y * s1; a1.z += v.z * s1; a1.w += v.w * s1;
    a2.x += v.x * s2; a2.y += v.y * s2; a2.z += v.z * s2; a2.w += v.w * s2;
  }
  a1.x += __shfl_down(a1.x, 32); a1.y += __shfl_down(a1.y, 32);
  a1.z += __shfl_down(a1.z, 32); a1.w += __shfl_down(a1.w, 32);
  a2.x += __shfl_down(a2.x, 32); a2.y += __shfl_down(a2.y, 32);
  a2.z += __shfl_down(a2.z, 32); a2.w += __shfl_down(a2.w, 32);
  if (lane < 32) {
    float wsc = wscale[node];
    float4 o1, o2;
    o1.x = a1.x * wsc; o1.y = a1.y * wsc; o1.z = a1.z * wsc; o1.w = a1.w * wsc;
    o2.x = a2.x * wsc; o2.y = a2.y * wsc; o2.z = a2.z * wsc; o2.w = a2.w * wsc;
    *((float4*)(out1 + (size_t)node * 128) + c) = o1;
    *((float4*)(out2 + (size_t)node * 128) + c) = o2;
  }
}

// out(n x DOUT) = A(n x 128) @ W(128 x DOUT) [+ bias] [+ res] [relu]
template <int DOUT, bool RELU, bool HAS_BIAS, bool ADD_RES>
__global__ __launch_bounds__(256) void gemm_kernel(
    const float* __restrict__ A, const float* __restrict__ W,
    const float* __restrict__ bias, const float* __restrict__ res,
    float* __restrict__ out, int n) {
  __shared__ float Wl[128 * DOUT];
  __shared__ float Al[32 * 128];
  for (int i = threadIdx.x; i < 128 * DOUT / 4; i += 256)
    ((float4*)Wl)[i] = ((const float4*)W)[i];
  int row0 = blockIdx.x * 32;
  for (int i = threadIdx.x; i < 32 * 32; i += 256) {
    int r = i >> 5, cc = i & 31;
    int gr = row0 + r;
    float4 v = make_float4(0.f, 0.f, 0.f, 0.f);
    if (gr < n) v = *((const float4*)(A + (size_t)gr * 128) + cc);
    *((float4*)(Al + r * 128) + cc) = v;
  }
  __syncthreads();
  constexpr int CG = DOUT / 4;
  constexpr int RG = 256 / CG;
  constexpr int RPT = 32 / RG;
  int tc = threadIdx.x % CG;
  int tr = threadIdx.x / CG;
  float4 acc[RPT];
#pragma unroll
  for (int r = 0; r < RPT; r++) acc[r] = make_float4(0.f, 0.f, 0.f, 0.f);
  for (int k0 = 0; k0 < 128; k0 += 4) {
    float4 av[RPT];
#pragma unroll
    for (int r = 0; r < RPT; r++)
      av[r] = *((const float4*)(Al + (tr * RPT + r) * 128 + k0));
#pragma unroll
    for (int kk = 0; kk < 4; kk++) {
      float4 w = *((const float4*)(Wl + (k0 + kk) * DOUT) + tc);
#pragma unroll
      for (int r = 0; r < RPT; r++) {
        float a = (&av[r].x)[kk];
        acc[r].x += a * w.x; acc[r].y += a * w.y;
        acc[r].z += a * w.z; acc[r].w += a * w.w;
      }
    }
  }
  float4 b = make_float4(0.f, 0.f, 0.f, 0.f);
  if (HAS_BIAS) b = ((const float4*)bias)[tc];
#pragma unroll
  for (int r = 0; r < RPT; r++) {
    int gr = row0 + tr * RPT + r;
    if (gr < n) {
      float4 o = acc[r];
      o.x += b.x; o.y += b.y; o.z += b.z; o.w += b.w;
      if (ADD_RES) {
        float4 rr = *((const float4*)(res + (size_t)gr * DOUT) + tc);
        o.x += rr.x; o.y += rr.y; o.z += rr.z; o.w += rr.w;
      }
      if (RELU) {
        o.x = fmaxf(o.x, 0.f); o.y = fmaxf(o.y, 0.f);
        o.z = fmaxf(o.z, 0.f); o.w = fmaxf(o.w, 0.f);
      }
      *((float4*)(out + (size_t)gr * DOUT) + tc) = o;
    }
  }
}

extern "C" void kernel_launch(void* const* d_in, const int* in_sizes, int n_in,
                              void* d_out, int out_size, void* d_ws, size_t ws_size,
                              hipStream_t stream) {
  const float* features = (const float*)d_in[0];
  const int*   src      = (const int*)d_in[1];
  const int*   dst      = (const int*)d_in[2];
  const float* W0 = (const float*)d_in[3];
  const float* b0 = (const float*)d_in[4];
  const float* W1 = (const float*)d_in[5];
  const float* b1 = (const float*)d_in[6];
  const float* W2 = (const float*)d_in[7];
  const float* b2 = (const float*)d_in[8];
  const float* W3 = (const float*)d_in[9];
  const float* b3 = (const float*)d_in[10];
  float* out = (float*)d_out;
  const int N = GN, E = GE;

  char* ws = (char*)d_ws;
  size_t off = 0;
  auto alloc = [&](size_t bytes) -> void* {
    void* p = ws + off;
    off = (off + bytes + 255) & ~(size_t)255;
    return p;
  };
  int*   indeg   = (int*)alloc((size_t)N * 4);
  int*   outdeg  = (int*)alloc((size_t)N * 4);
  float* innorm  = (float*)alloc((size_t)N * 4);
  float* outnorm = (float*)alloc((size_t)N * 4);
  int*   offsets = (int*)alloc((size_t)(N + 1) * 4);
  int*   cursor  = (int*)alloc((size_t)N * 4);
  int*   csr     = (int*)alloc((size_t)E * 4);
  int*   bsums   = (int*)alloc((size_t)256 * 4);
  int*   bpref   = (int*)alloc((size_t)256 * 4);
  float* res     = (float*)alloc((size_t)N * 128 * 4);
  float* bufA    = (float*)alloc((size_t)N * 128 * 4);
  float* bufB    = (float*)alloc((size_t)N * 128 * 4);
  float* Y       = (float*)alloc((size_t)N * 64 * 4);
  (void)ws_size; (void)in_sizes; (void)n_in; (void)out_size;

  hipMemsetAsync(indeg, 0, (size_t)N * 4, stream);
  hipMemsetAsync(outdeg, 0, (size_t)N * 4, stream);

  degrees_kernel<<<(E + 255) / 256, 256, 0, stream>>>(src, dst, indeg, outdeg, E);
  norms_kernel<<<(N + 255) / 256, 256, 0, stream>>>(indeg, outdeg, innorm, outnorm, N);

  int nb = (N + SCAN_CHUNK - 1) / SCAN_CHUNK;  // 49
  scan_blocksums<<<nb, 256, 0, stream>>>(indeg, bsums, N);
  scan_bsums<<<1, 64, 0, stream>>>(bsums, bpref, nb, offsets, N);
  scan_final<<<nb, 256, 0, stream>>>(indeg, bpref, offsets, cursor, N);

  fill_csr_kernel<<<(E + 255) / 256, 256, 0, stream>>>(src, dst, cursor, csr, E);

  int aggGrid  = (N + 3) / 4;
  int gemmGrid = (N + 31) / 32;

  // t0 = innorm.*agg(outnorm.*f); res = innorm.*agg(innorm.*f) — one gather pass
  aggregate_dual_kernel<<<aggGrid, 256, 0, stream>>>(
      features, outnorm, innorm, innorm, offsets, csr, bufA, res, N);
  // h0 = relu(t0 @ W0 + b0)
  gemm_kernel<128, true, true, false><<<gemmGrid, 256, 0, stream>>>(
      bufA, W0, b0, nullptr, bufB, N);
  // t1 = innorm .* agg(outnorm .* h0)
  aggregate_kernel<128, false><<<aggGrid, 256, 0, stream>>>(
      bufB, outnorm, innorm, nullptr, offsets, csr, bufA, N);
  // h1 = relu(t1 @ W1 + b1 + res)
  gemm_kernel<128, true, true, true><<<gemmGrid, 256, 0, stream>>>(
      bufA, W1, b1, res, bufB, N);
  // t2 = innorm .* agg(outnorm .* h1)
  aggregate_kernel<128, false><<<aggGrid, 256, 0, stream>>>(
      bufB, outnorm, innorm, nullptr, offsets, csr, bufA, N);
  // h2 = relu(t2 @ W2 + b2 + res)
  gemm_kernel<128, true, true, true><<<gemmGrid, 256, 0, stream>>>(
      bufA, W2, b2, res, bufB, N);
  // Y = h2 @ W3  (matmul commutes with aggregation; 64-wide aggregate after)
  gemm_kernel<64, false, false, false><<<gemmGrid, 256, 0, stream>>>(
      bufB, W3, nullptr, nullptr, Y, N);
  // out = innorm .* agg(outnorm .* Y) + b3
  aggregate_kernel<64, true><<<aggGrid, 256, 0, stream>>>(
      Y, outnorm, innorm, b3, offsets, csr, out, N);
}

// Round 3
// 548.405 us; speedup vs baseline: 1.3029x; 1.0444x over previous
//
#include <hip/hip_runtime.h>

// GResNet GCN: N=50000, E=800000, d=128 (out 64).
// R2 changes: (1) 8-way replicated histograms/cursors to kill same-line atomic
// serialization in degrees + CSR fill, (2) aggregate gathers restructured to
// 4 edge-slots/wave x 2 float4/lane + x2 unroll (16 row-loads in flight),
// (3) norms fused with replica reduce/prefix.

#define GN 50000
#define GE 800000
#define NREP 8
#define SCAN_CHUNK 1024

__device__ __forceinline__ void fma4(float4& a, float4 v, float s) {
  a.x += v.x * s; a.y += v.y * s; a.z += v.z * s; a.w += v.w * s;
}

// ---- degrees via 8-way replicated histograms (replica = e & 7) ----
__global__ void degrees_rep_kernel(const int* __restrict__ src, const int* __restrict__ dst,
                                   int* __restrict__ histIn, int* __restrict__ histOut, int E) {
  int e = blockIdx.x * blockDim.x + threadIdx.x;
  if (e < E) {
    int r = e & (NREP - 1);
    atomicAdd(&histIn[r * GN + dst[e]], 1);
    atomicAdd(&histOut[r * GN + src[e]], 1);
  }
}

// Per node: indeg = sum_r histIn[r][node]; convert histIn to replica-exclusive
// prefix in place; norms from totals.
__global__ void norms_reduce_kernel(int* __restrict__ histIn, const int* __restrict__ histOut,
                                    int* __restrict__ indeg, float* __restrict__ innorm,
                                    float* __restrict__ outnorm, int n) {
  int i = blockIdx.x * blockDim.x + threadIdx.x;
  if (i >= n) return;
  int v[NREP];
  int s = 0;
#pragma unroll
  for (int r = 0; r < NREP; r++) { v[r] = histIn[r * GN + i]; }
  int run = 0;
#pragma unroll
  for (int r = 0; r < NREP; r++) { histIn[r * GN + i] = run; run += v[r]; }
  s = run;
  indeg[i] = s;
  innorm[i] = rsqrtf((float)max(s, 1));
  int so = 0;
#pragma unroll
  for (int r = 0; r < NREP; r++) so += histOut[r * GN + i];
  outnorm[i] = rsqrtf((float)max(so, 1));
}

// ---- hierarchical scan over indeg -> offsets ----
__global__ __launch_bounds__(256) void scan_blocksums(const int* __restrict__ deg,
                                                      int* __restrict__ bsums, int n) {
  int tid = threadIdx.x;
  int i = blockIdx.x * SCAN_CHUNK + tid * 4;
  int s = 0;
  if (i + 3 < n) {
    int4 v = *(const int4*)(deg + i);
    s = v.x + v.y + v.z + v.w;
  } else {
    for (int j = 0; j < 4; j++) if (i + j < n) s += deg[i + j];
  }
  for (int off = 32; off; off >>= 1) s += __shfl_down(s, off);
  __shared__ int ws[4];
  if ((tid & 63) == 0) ws[tid >> 6] = s;
  __syncthreads();
  if (tid == 0) bsums[blockIdx.x] = ws[0] + ws[1] + ws[2] + ws[3];
}

__global__ void scan_bsums(const int* __restrict__ bsums, int* __restrict__ bpref,
                           int nb, int* __restrict__ offsets, int n) {
  int tid = threadIdx.x;
  int v = (tid < nb) ? bsums[tid] : 0;
  int incl = v;
  for (int off = 1; off < 64; off <<= 1) {
    int t = __shfl_up(incl, off);
    if (tid >= off) incl += t;
  }
  if (tid < nb) bpref[tid] = incl - v;
  if (tid == 63) offsets[n] = incl;
}

__global__ __launch_bounds__(256) void scan_final(const int* __restrict__ deg,
                                                  const int* __restrict__ bpref,
                                                  int* __restrict__ offsets, int n) {
  int tid = threadIdx.x;
  int i = blockIdx.x * SCAN_CHUNK + tid * 4;
  int v[4];
#pragma unroll
  for (int j = 0; j < 4; j++) v[j] = (i + j < n) ? deg[i + j] : 0;
  int tsum = v[0] + v[1] + v[2] + v[3];
  int incl = tsum;
  for (int off = 1; off < 64; off <<= 1) {
    int t = __shfl_up(incl, off);
    if ((tid & 63) >= off) incl += t;
  }
  __shared__ int wsum[4];
  int wid = tid >> 6, lane = tid & 63;
  if (lane == 63) wsum[wid] = incl;
  __syncthreads();
  int wpref = 0;
  for (int w = 0; w < wid; w++) wpref += wsum[w];
  int run = bpref[blockIdx.x] + wpref + incl - tsum;
#pragma unroll
  for (int j = 0; j < 4; j++) {
    if (i + j < n) offsets[i + j] = run;
    run += v[j];
  }
}

// cursor[r][node] = offsets[node] + replica-prefix (histIn now holds prefix)
__global__ void cursor_init_kernel(const int* __restrict__ offsets,
                                   const int* __restrict__ histPref,
                                   int* __restrict__ cursor, int n) {
  int i = blockIdx.x * blockDim.x + threadIdx.x;
  if (i >= n) return;
  int base = offsets[i];
#pragma unroll
  for (int r = 0; r < NREP; r++) cursor[r * GN + i] = base + histPref[r * GN + i];
}

__global__ void fill_csr_rep_kernel(const int* __restrict__ src, const int* __restrict__ dst,
                                    int* __restrict__ cursor, int* __restrict__ csr, int E) {
  int e = blockIdx.x * blockDim.x + threadIdx.x;
  if (e < E) {
    int r = e & (NREP - 1);
    int pos = atomicAdd(&cursor[r * GN + dst[e]], 1);
    csr[pos] = src[e];
  }
}

// ---- aggregates ----
// D=128, one wave/node: 16 lanes per row (2 float4 each), 4 edge slots, x2 unroll.
__global__ __launch_bounds__(256) void aggregate128_kernel(
    const float* __restrict__ h, const float* __restrict__ gscale,
    const float* __restrict__ wscale, const int* __restrict__ offsets,
    const int* __restrict__ csr, float* __restrict__ out, int n) {
  int node = blockIdx.x * 4 + (threadIdx.x >> 6);
  if (node >= n) return;
  int lane = threadIdx.x & 63;
  int c = lane & 15;
  int p = lane >> 4;
  int s = offsets[node], e = offsets[node + 1];
  float4 a0 = make_float4(0.f, 0.f, 0.f, 0.f);
  float4 a1 = make_float4(0.f, 0.f, 0.f, 0.f);
  int i = s + p;
  for (; i + 4 < e; i += 8) {
    int sn0 = csr[i], sn1 = csr[i + 4];
    float s0 = gscale[sn0], s1 = gscale[sn1];
    const float4* r0 = (const float4*)(h + (size_t)sn0 * 128);
    const float4* r1 = (const float4*)(h + (size_t)sn1 * 128);
    float4 v00 = r0[c], v01 = r0[c + 16];
    float4 v10 = r1[c], v11 = r1[c + 16];
    fma4(a0, v00, s0); fma4(a1, v01, s0);
    fma4(a0, v10, s1); fma4(a1, v11, s1);
  }
  if (i < e) {
    int sn = csr[i];
    float sc = gscale[sn];
    const float4* r0 = (const float4*)(h + (size_t)sn * 128);
    fma4(a0, r0[c], sc); fma4(a1, r0[c + 16], sc);
  }
#pragma unroll
  for (int off = 32; off >= 16; off >>= 1) {
    a0.x += __shfl_down(a0.x, off); a0.y += __shfl_down(a0.y, off);
    a0.z += __shfl_down(a0.z, off); a0.w += __shfl_down(a0.w, off);
    a1.x += __shfl_down(a1.x, off); a1.y += __shfl_down(a1.y, off);
    a1.z += __shfl_down(a1.z, off); a1.w += __shfl_down(a1.w, off);
  }
  if (lane < 16) {
    float w = wscale[node];
    float4 o0 = make_float4(a0.x * w, a0.y * w, a0.z * w, a0.w * w);
    float4 o1 = make_float4(a1.x * w, a1.y * w, a1.z * w, a1.w * w);
    float4* orow = (float4*)(out + (size_t)node * 128);
    orow[c] = o0; orow[c + 16] = o1;
  }
}

// Dual (D=128): out1 = w.*agg(g1.*h), out2 = w.*agg(g2.*h) in one gather pass.
__global__ __launch_bounds__(256) void aggregate_dual_kernel(
    const float* __restrict__ h, const float* __restrict__ g1,
    const float* __restrict__ g2, const float* __restrict__ wscale,
    const int* __restrict__ offsets, const int* __restrict__ csr,
    float* __restrict__ out1, float* __restrict__ out2, int n) {
  int node = blockIdx.x * 4 + (threadIdx.x >> 6);
  if (node >= n) return;
  int lane = threadIdx.x & 63;
  int c = lane & 15;
  int p = lane >> 4;
  int s = offsets[node], e = offsets[node + 1];
  float4 a10 = make_float4(0.f, 0.f, 0.f, 0.f);
  float4 a11 = make_float4(0.f, 0.f, 0.f, 0.f);
  float4 a20 = make_float4(0.f, 0.f, 0.f, 0.f);
  float4 a21 = make_float4(0.f, 0.f, 0.f, 0.f);
  int i = s + p;
  for (; i + 4 < e; i += 8) {
    int sn0 = csr[i], sn1 = csr[i + 4];
    float g1a = g1[sn0], g2a = g2[sn0];
    float g1b = g1[sn1], g2b = g2[sn1];
    const float4* r0 = (const float4*)(h + (size_t)sn0 * 128);
    const float4* r1 = (const float4*)(h + (size_t)sn1 * 128);
    float4 v00 = r0[c], v01 = r0[c + 16];
    float4 v10 = r1[c], v11 = r1[c + 16];
    fma4(a10, v00, g1a); fma4(a11, v01, g1a);
    fma4(a20, v00, g2a); fma4(a21, v01, g2a);
    fma4(a10, v10, g1b); fma4(a11, v11, g1b);
    fma4(a20, v10, g2b); fma4(a21, v11, g2b);
  }
  if (i < e) {
    int sn = csr[i];
    float g1a = g1[sn], g2a = g2[sn];
    const float4* r0 = (const float4*)(h + (size_t)sn * 128);
    float4 v0 = r0[c], v1 = r0[c + 16];
    fma4(a10, v0, g1a); fma4(a11, v1, g1a);
    fma4(a20, v0, g2a); fma4(a21, v1, g2a);
  }
#pragma unroll
  for (int off = 32; off >= 16; off >>= 1) {
    a10.x += __shfl_down(a10.x, off); a10.y += __shfl_down(a10.y, off);
    a10.z += __shfl_down(a10.z, off); a10.w += __shfl_down(a10.w, off);
    a11.x += __shfl_down(a11.x, off); a11.y += __shfl_down(a11.y, off);
    a11.z += __shfl_down(a11.z, off); a11.w += __shfl_down(a11.w, off);
    a20.x += __shfl_down(a20.x, off); a20.y += __shfl_down(a20.y, off);
    a20.z += __shfl_down(a20.z, off); a20.w += __shfl_down(a20.w, off);
    a21.x += __shfl_down(a21.x, off); a21.y += __shfl_down(a21.y, off);
    a21.z += __shfl_down(a21.z, off); a21.w += __shfl_down(a21.w, off);
  }
  if (lane < 16) {
    float w = wscale[node];
    float4* o1 = (float4*)(out1 + (size_t)node * 128);
    float4* o2 = (float4*)(out2 + (size_t)node * 128);
    o1[c]      = make_float4(a10.x * w, a10.y * w, a10.z * w, a10.w * w);
    o1[c + 16] = make_float4(a11.x * w, a11.y * w, a11.z * w, a11.w * w);
    o2[c]      = make_float4(a20.x * w, a20.y * w, a20.z * w, a20.w * w);
    o2[c + 16] = make_float4(a21.x * w, a21.y * w, a21.z * w, a21.w * w);
  }
}

// D=64 aggregate (final layer, + bias): 16 lanes/row, 4 edge slots.
__global__ __launch_bounds__(256) void aggregate64_kernel(
    const float* __restrict__ h, const float* __restrict__ gscale,
    const float* __restrict__ wscale, const float* __restrict__ bias,
    const int* __restrict__ offsets, const int* __restrict__ csr,
    float* __restrict__ out, int n) {
  int node = blockIdx.x * 4 + (threadIdx.x >> 6);
  if (node >= n) return;
  int lane = threadIdx.x & 63;
  int c = lane & 15;
  int p = lane >> 4;
  int s = offsets[node], e = offsets[node + 1];
  float4 acc = make_float4(0.f, 0.f, 0.f, 0.f);
  int i = s + p;
  for (; i + 4 < e; i += 8) {
    int sn0 = csr[i], sn1 = csr[i + 4];
    float s0 = gscale[sn0], s1 = gscale[sn1];
    float4 v0 = *((const float4*)(h + (size_t)sn0 * 64) + c);
    float4 v1 = *((const float4*)(h + (size_t)sn1 * 64) + c);
    fma4(acc, v0, s0); fma4(acc, v1, s1);
  }
  if (i < e) {
    int sn = csr[i];
    fma4(acc, *((const float4*)(h + (size_t)sn * 64) + c), gscale[sn]);
  }
#pragma unroll
  for (int off = 32; off >= 16; off >>= 1) {
    acc.x += __shfl_down(acc.x, off); acc.y += __shfl_down(acc.y, off);
    acc.z += __shfl_down(acc.z, off); acc.w += __shfl_down(acc.w, off);
  }
  if (lane < 16) {
    float w = wscale[node];
    float4 b = ((const float4*)bias)[c];
    float4 o = make_float4(acc.x * w + b.x, acc.y * w + b.y,
                           acc.z * w + b.z, acc.w * w + b.w);
    *((float4*)(out + (size_t)node * 64) + c) = o;
  }
}

// out(n x DOUT) = A(n x 128) @ W(128 x DOUT) [+ bias] [+ res] [relu]
template <int DOUT, bool RELU, bool HAS_BIAS, bool ADD_RES>
__global__ __launch_bounds__(256) void gemm_kernel(
    const float* __restrict__ A, const float* __restrict__ W,
    const float* __restrict__ bias, const float* __restrict__ res,
    float* __restrict__ out, int n) {
  __shared__ float Wl[128 * DOUT];
  __shared__ float Al[32 * 128];
  for (int i = threadIdx.x; i < 128 * DOUT / 4; i += 256)
    ((float4*)Wl)[i] = ((const float4*)W)[i];
  int row0 = blockIdx.x * 32;
  for (int i = threadIdx.x; i < 32 * 32; i += 256) {
    int r = i >> 5, cc = i & 31;
    int gr = row0 + r;
    float4 v = make_float4(0.f, 0.f, 0.f, 0.f);
    if (gr < n) v = *((const float4*)(A + (size_t)gr * 128) + cc);
    *((float4*)(Al + r * 128) + cc) = v;
  }
  __syncthreads();
  constexpr int CG = DOUT / 4;
  constexpr int RG = 256 / CG;
  constexpr int RPT = 32 / RG;
  int tc = threadIdx.x % CG;
  int tr = threadIdx.x / CG;
  float4 acc[RPT];
#pragma unroll
  for (int r = 0; r < RPT; r++) acc[r] = make_float4(0.f, 0.f, 0.f, 0.f);
  for (int k0 = 0; k0 < 128; k0 += 4) {
    float4 av[RPT];
#pragma unroll
    for (int r = 0; r < RPT; r++)
      av[r] = *((const float4*)(Al + (tr * RPT + r) * 128 + k0));
#pragma unroll
    for (int kk = 0; kk < 4; kk++) {
      float4 w = *((const float4*)(Wl + (k0 + kk) * DOUT) + tc);
#pragma unroll
      for (int r = 0; r < RPT; r++) {
        float a = (&av[r].x)[kk];
        acc[r].x += a * w.x; acc[r].y += a * w.y;
        acc[r].z += a * w.z; acc[r].w += a * w.w;
      }
    }
  }
  float4 b = make_float4(0.f, 0.f, 0.f, 0.f);
  if (HAS_BIAS) b = ((const float4*)bias)[tc];
#pragma unroll
  for (int r = 0; r < RPT; r++) {
    int gr = row0 + tr * RPT + r;
    if (gr < n) {
      float4 o = acc[r];
      o.x += b.x; o.y += b.y; o.z += b.z; o.w += b.w;
      if (ADD_RES) {
        float4 rr = *((const float4*)(res + (size_t)gr * DOUT) + tc);
        o.x += rr.x; o.y += rr.y; o.z += rr.z; o.w += rr.w;
      }
      if (RELU) {
        o.x = fmaxf(o.x, 0.f); o.y = fmaxf(o.y, 0.f);
        o.z = fmaxf(o.z, 0.f); o.w = fmaxf(o.w, 0.f);
      }
      *((float4*)(out + (size_t)gr * DOUT) + tc) = o;
    }
  }
}

extern "C" void kernel_launch(void* const* d_in, const int* in_sizes, int n_in,
                              void* d_out, int out_size, void* d_ws, size_t ws_size,
                              hipStream_t stream) {
  const float* features = (const float*)d_in[0];
  const int*   src      = (const int*)d_in[1];
  const int*   dst      = (const int*)d_in[2];
  const float* W0 = (const float*)d_in[3];
  const float* b0 = (const float*)d_in[4];
  const float* W1 = (const float*)d_in[5];
  const float* b1 = (const float*)d_in[6];
  const float* W2 = (const float*)d_in[7];
  const float* b2 = (const float*)d_in[8];
  const float* W3 = (const float*)d_in[9];
  const float* b3 = (const float*)d_in[10];
  float* out = (float*)d_out;
  const int N = GN, E = GE;

  char* ws = (char*)d_ws;
  size_t off = 0;
  auto alloc = [&](size_t bytes) -> void* {
    void* p = ws + off;
    off = (off + bytes + 255) & ~(size_t)255;
    return p;
  };
  int*   histIn  = (int*)alloc((size_t)NREP * N * 4);
  int*   histOut = (int*)alloc((size_t)NREP * N * 4);
  int*   cursor  = (int*)alloc((size_t)NREP * N * 4);
  int*   indeg   = (int*)alloc((size_t)N * 4);
  float* innorm  = (float*)alloc((size_t)N * 4);
  float* outnorm = (float*)alloc((size_t)N * 4);
  int*   offsets = (int*)alloc((size_t)(N + 1) * 4);
  int*   csr     = (int*)alloc((size_t)E * 4);
  int*   bsums   = (int*)alloc((size_t)256 * 4);
  int*   bpref   = (int*)alloc((size_t)256 * 4);
  float* res     = (float*)alloc((size_t)N * 128 * 4);
  float* bufA    = (float*)alloc((size_t)N * 128 * 4);
  float* bufB    = (float*)alloc((size_t)N * 128 * 4);
  float* Y       = (float*)alloc((size_t)N * 64 * 4);
  (void)ws_size; (void)in_sizes; (void)n_in; (void)out_size;

  hipMemsetAsync(histIn, 0, (size_t)NREP * N * 4, stream);
  hipMemsetAsync(histOut, 0, (size_t)NREP * N * 4, stream);

  degrees_rep_kernel<<<(E + 255) / 256, 256, 0, stream>>>(src, dst, histIn, histOut, E);
  norms_reduce_kernel<<<(N + 255) / 256, 256, 0, stream>>>(
      histIn, histOut, indeg, innorm, outnorm, N);

  int nb = (N + SCAN_CHUNK - 1) / SCAN_CHUNK;  // 49
  scan_blocksums<<<nb, 256, 0, stream>>>(indeg, bsums, N);
  scan_bsums<<<1, 64, 0, stream>>>(bsums, bpref, nb, offsets, N);
  scan_final<<<nb, 256, 0, stream>>>(indeg, bpref, offsets, N);

  cursor_init_kernel<<<(N + 255) / 256, 256, 0, stream>>>(offsets, histIn, cursor, N);
  fill_csr_rep_kernel<<<(E + 255) / 256, 256, 0, stream>>>(src, dst, cursor, csr, E);

  int aggGrid  = (N + 3) / 4;
  int gemmGrid = (N + 31) / 32;

  // t0 = innorm.*agg(outnorm.*f); res = innorm.*agg(innorm.*f) — one gather pass
  aggregate_dual_kernel<<<aggGrid, 256, 0, stream>>>(
      features, outnorm, innorm, innorm, offsets, csr, bufA, res, N);
  // h0 = relu(t0 @ W0 + b0)
  gemm_kernel<128, true, true, false><<<gemmGrid, 256, 0, stream>>>(
      bufA, W0, b0, nullptr, bufB, N);
  // t1 = innorm .* agg(outnorm .* h0)
  aggregate128_kernel<<<aggGrid, 256, 0, stream>>>(
      bufB, outnorm, innorm, offsets, csr, bufA, N);
  // h1 = relu(t1 @ W1 + b1 + res)
  gemm_kernel<128, true, true, true><<<gemmGrid, 256, 0, stream>>>(
      bufA, W1, b1, res, bufB, N);
  // t2 = innorm .* agg(outnorm .* h1)
  aggregate128_kernel<<<aggGrid, 256, 0, stream>>>(
      bufB, outnorm, innorm, offsets, csr, bufA, N);
  // h2 = relu(t2 @ W2 + b2 + res)
  gemm_kernel<128, true, true, true><<<gemmGrid, 256, 0, stream>>>(
      bufA, W2, b2, res, bufB, N);
  // Y = h2 @ W3  (matmul commutes with aggregation; 64-wide aggregate after)
  gemm_kernel<64, false, false, false><<<gemmGrid, 256, 0, stream>>>(
      bufB, W3, nullptr, nullptr, Y, N);
  // out = innorm .* agg(outnorm .* Y) + b3
  aggregate64_kernel<<<aggGrid, 256, 0, stream>>>(
      Y, outnorm, innorm, b3, offsets, csr, out, N);
}

// Round 4
// 506.739 us; speedup vs baseline: 1.4100x; 1.0822x over previous
//
#include <hip/hip_runtime.h>

// GResNet GCN: N=50000, E=800000, d=128 (out 64).
// R4 change: degrees via LDS-privatized packed-uint16 histograms (256 blocks:
// 64 edge-slices x 2 directions x 2 node-halves, 50KB LDS each) + tree reduce.
// Kills the 1.6M global atomics whose per-atomic line write-back (50MB) made
// degrees_rep 62us at 0.4% VALUBusy. Replica cursors removed; fill_csr uses a
// single cursor initialized by async D2D copy of offsets.

#define GN 50000
#define GE 800000
#define SCAN_CHUNK 1024
#define DEG_BLOCKS 64
#define DEG_SLICE 12500      // GE / DEG_BLOCKS
#define HALF_NODES 25000
#define HALF_WORDS 12500     // packed uint16 pairs

__device__ __forceinline__ void fma4(float4& a, float4 v, float s) {
  a.x += v.x * s; a.y += v.y * s; a.z += v.z * s; a.w += v.w * s;
}

// ---- degrees via LDS histograms ----
// blockIdx: b = bits[0:6) edge slice, half = bit 6, dir = bit 7 (0=dst/in, 1=src/out)
__global__ __launch_bounds__(256) void degrees_lds_kernel(
    const int* __restrict__ src, const int* __restrict__ dst,
    unsigned int* __restrict__ partials, int E) {
  __shared__ unsigned int hist[HALF_WORDS];
  for (int i = threadIdx.x; i < HALF_WORDS; i += 256) hist[i] = 0u;
  __syncthreads();
  int b    = blockIdx.x & 63;
  int half = (blockIdx.x >> 6) & 1;
  int dir  = blockIdx.x >> 7;
  const int* __restrict__ idx = dir ? src : dst;
  int lo = half * HALF_NODES, hi = lo + HALF_NODES;
  int s = b * DEG_SLICE;
  int e = min(s + DEG_SLICE, E);
  for (int i = s + threadIdx.x; i < e; i += 256) {
    int node = idx[i];
    if (node >= lo && node < hi) {
      int local = node - lo;
      atomicAdd(&hist[local >> 1], 1u << ((local & 1) << 4));
    }
  }
  __syncthreads();
  unsigned int* outp = partials + (((size_t)dir * 2 + half) * DEG_BLOCKS + b) * HALF_WORDS;
  for (int i = threadIdx.x; i < HALF_WORDS; i += 256) outp[i] = hist[i];
}

__global__ void degrees_reduce_kernel(const unsigned int* __restrict__ partials,
                                      int* __restrict__ indeg, float* __restrict__ innorm,
                                      float* __restrict__ outnorm) {
  int g = blockIdx.x * blockDim.x + threadIdx.x;   // [0, 2*HALF_WORDS)
  if (g >= 2 * HALF_WORDS) return;
  int half = (g >= HALF_WORDS) ? 1 : 0;
  int w = g - half * HALF_WORDS;
  unsigned int inLo = 0, inHi = 0, outLo = 0, outHi = 0;
  const unsigned int* pIn  = partials + ((size_t)(0 * 2 + half) * DEG_BLOCKS) * HALF_WORDS + w;
  const unsigned int* pOut = partials + ((size_t)(1 * 2 + half) * DEG_BLOCKS) * HALF_WORDS + w;
#pragma unroll 4
  for (int b = 0; b < DEG_BLOCKS; b++) {
    unsigned int v = pIn[(size_t)b * HALF_WORDS];
    inLo += v & 0xffffu; inHi += v >> 16;
    unsigned int u = pOut[(size_t)b * HALF_WORDS];
    outLo += u & 0xffffu; outHi += u >> 16;
  }
  int n0 = half * HALF_NODES + 2 * w;
  indeg[n0]     = (int)inLo;
  indeg[n0 + 1] = (int)inHi;
  innorm[n0]      = rsqrtf((float)max((int)inLo, 1));
  innorm[n0 + 1]  = rsqrtf((float)max((int)inHi, 1));
  outnorm[n0]     = rsqrtf((float)max((int)outLo, 1));
  outnorm[n0 + 1] = rsqrtf((float)max((int)outHi, 1));
}

// ---- hierarchical scan over indeg -> offsets ----
__global__ __launch_bounds__(256) void scan_blocksums(const int* __restrict__ deg,
                                                      int* __restrict__ bsums, int n) {
  int tid = threadIdx.x;
  int i = blockIdx.x * SCAN_CHUNK + tid * 4;
  int s = 0;
  if (i + 3 < n) {
    int4 v = *(const int4*)(deg + i);
    s = v.x + v.y + v.z + v.w;
  } else {
    for (int j = 0; j < 4; j++) if (i + j < n) s += deg[i + j];
  }
  for (int off = 32; off; off >>= 1) s += __shfl_down(s, off);
  __shared__ int ws[4];
  if ((tid & 63) == 0) ws[tid >> 6] = s;
  __syncthreads();
  if (tid == 0) bsums[blockIdx.x] = ws[0] + ws[1] + ws[2] + ws[3];
}

__global__ void scan_bsums(const int* __restrict__ bsums, int* __restrict__ bpref,
                           int nb, int* __restrict__ offsets, int n) {
  int tid = threadIdx.x;
  int v = (tid < nb) ? bsums[tid] : 0;
  int incl = v;
  for (int off = 1; off < 64; off <<= 1) {
    int t = __shfl_up(incl, off);
    if (tid >= off) incl += t;
  }
  if (tid < nb) bpref[tid] = incl - v;
  if (tid == 63) offsets[n] = incl;
}

__global__ __launch_bounds__(256) void scan_final(const int* __restrict__ deg,
                                                  const int* __restrict__ bpref,
                                                  int* __restrict__ offsets, int n) {
  int tid = threadIdx.x;
  int i = blockIdx.x * SCAN_CHUNK + tid * 4;
  int v[4];
#pragma unroll
  for (int j = 0; j < 4; j++) v[j] = (i + j < n) ? deg[i + j] : 0;
  int tsum = v[0] + v[1] + v[2] + v[3];
  int incl = tsum;
  for (int off = 1; off < 64; off <<= 1) {
    int t = __shfl_up(incl, off);
    if ((tid & 63) >= off) incl += t;
  }
  __shared__ int wsum[4];
  int wid = tid >> 6, lane = tid & 63;
  if (lane == 63) wsum[wid] = incl;
  __syncthreads();
  int wpref = 0;
  for (int w = 0; w < wid; w++) wpref += wsum[w];
  int run = bpref[blockIdx.x] + wpref + incl - tsum;
#pragma unroll
  for (int j = 0; j < 4; j++) {
    if (i + j < n) offsets[i + j] = run;
    run += v[j];
  }
}

__global__ void fill_csr_kernel(const int* __restrict__ src, const int* __restrict__ dst,
                                int* __restrict__ cursor, int* __restrict__ csr, int E) {
  int e = blockIdx.x * blockDim.x + threadIdx.x;
  if (e < E) {
    int pos = atomicAdd(&cursor[dst[e]], 1);
    csr[pos] = src[e];
  }
}

// ---- aggregates ----
// D=128, one wave/node: 16 lanes per row (2 float4 each), 4 edge slots, x2 unroll.
__global__ __launch_bounds__(256) void aggregate128_kernel(
    const float* __restrict__ h, const float* __restrict__ gscale,
    const float* __restrict__ wscale, const int* __restrict__ offsets,
    const int* __restrict__ csr, float* __restrict__ out, int n) {
  int node = blockIdx.x * 4 + (threadIdx.x >> 6);
  if (node >= n) return;
  int lane = threadIdx.x & 63;
  int c = lane & 15;
  int p = lane >> 4;
  int s = offsets[node], e = offsets[node + 1];
  float4 a0 = make_float4(0.f, 0.f, 0.f, 0.f);
  float4 a1 = make_float4(0.f, 0.f, 0.f, 0.f);
  int i = s + p;
  for (; i + 4 < e; i += 8) {
    int sn0 = csr[i], sn1 = csr[i + 4];
    float s0 = gscale[sn0], s1 = gscale[sn1];
    const float4* r0 = (const float4*)(h + (size_t)sn0 * 128);
    const float4* r1 = (const float4*)(h + (size_t)sn1 * 128);
    float4 v00 = r0[c], v01 = r0[c + 16];
    float4 v10 = r1[c], v11 = r1[c + 16];
    fma4(a0, v00, s0); fma4(a1, v01, s0);
    fma4(a0, v10, s1); fma4(a1, v11, s1);
  }
  if (i < e) {
    int sn = csr[i];
    float sc = gscale[sn];
    const float4* r0 = (const float4*)(h + (size_t)sn * 128);
    fma4(a0, r0[c], sc); fma4(a1, r0[c + 16], sc);
  }
#pragma unroll
  for (int off = 32; off >= 16; off >>= 1) {
    a0.x += __shfl_down(a0.x, off); a0.y += __shfl_down(a0.y, off);
    a0.z += __shfl_down(a0.z, off); a0.w += __shfl_down(a0.w, off);
    a1.x += __shfl_down(a1.x, off); a1.y += __shfl_down(a1.y, off);
    a1.z += __shfl_down(a1.z, off); a1.w += __shfl_down(a1.w, off);
  }
  if (lane < 16) {
    float w = wscale[node];
    float4 o0 = make_float4(a0.x * w, a0.y * w, a0.z * w, a0.w * w);
    float4 o1 = make_float4(a1.x * w, a1.y * w, a1.z * w, a1.w * w);
    float4* orow = (float4*)(out + (size_t)node * 128);
    orow[c] = o0; orow[c + 16] = o1;
  }
}

// Dual (D=128): out1 = w.*agg(g1.*h), out2 = w.*agg(g2.*h) in one gather pass.
__global__ __launch_bounds__(256) void aggregate_dual_kernel(
    const float* __restrict__ h, const float* __restrict__ g1,
    const float* __restrict__ g2, const float* __restrict__ wscale,
    const int* __restrict__ offsets, const int* __restrict__ csr,
    float* __restrict__ out1, float* __restrict__ out2, int n) {
  int node = blockIdx.x * 4 + (threadIdx.x >> 6);
  if (node >= n) return;
  int lane = threadIdx.x & 63;
  int c = lane & 15;
  int p = lane >> 4;
  int s = offsets[node], e = offsets[node + 1];
  float4 a10 = make_float4(0.f, 0.f, 0.f, 0.f);
  float4 a11 = make_float4(0.f, 0.f, 0.f, 0.f);
  float4 a20 = make_float4(0.f, 0.f, 0.f, 0.f);
  float4 a21 = make_float4(0.f, 0.f, 0.f, 0.f);
  int i = s + p;
  for (; i + 4 < e; i += 8) {
    int sn0 = csr[i], sn1 = csr[i + 4];
    float g1a = g1[sn0], g2a = g2[sn0];
    float g1b = g1[sn1], g2b = g2[sn1];
    const float4* r0 = (const float4*)(h + (size_t)sn0 * 128);
    const float4* r1 = (const float4*)(h + (size_t)sn1 * 128);
    float4 v00 = r0[c], v01 = r0[c + 16];
    float4 v10 = r1[c], v11 = r1[c + 16];
    fma4(a10, v00, g1a); fma4(a11, v01, g1a);
    fma4(a20, v00, g2a); fma4(a21, v01, g2a);
    fma4(a10, v10, g1b); fma4(a11, v11, g1b);
    fma4(a20, v10, g2b); fma4(a21, v11, g2b);
  }
  if (i < e) {
    int sn = csr[i];
    float g1a = g1[sn], g2a = g2[sn];
    const float4* r0 = (const float4*)(h + (size_t)sn * 128);
    float4 v0 = r0[c], v1 = r0[c + 16];
    fma4(a10, v0, g1a); fma4(a11, v1, g1a);
    fma4(a20, v0, g2a); fma4(a21, v1, g2a);
  }
#pragma unroll
  for (int off = 32; off >= 16; off >>= 1) {
    a10.x += __shfl_down(a10.x, off); a10.y += __shfl_down(a10.y, off);
    a10.z += __shfl_down(a10.z, off); a10.w += __shfl_down(a10.w, off);
    a11.x += __shfl_down(a11.x, off); a11.y += __shfl_down(a11.y, off);
    a11.z += __shfl_down(a11.z, off); a11.w += __shfl_down(a11.w, off);
    a20.x += __shfl_down(a20.x, off); a20.y += __shfl_down(a20.y, off);
    a20.z += __shfl_down(a20.z, off); a20.w += __shfl_down(a20.w, off);
    a21.x += __shfl_down(a21.x, off); a21.y += __shfl_down(a21.y, off);
    a21.z += __shfl_down(a21.z, off); a21.w += __shfl_down(a21.w, off);
  }
  if (lane < 16) {
    float w = wscale[node];
    float4* o1 = (float4*)(out1 + (size_t)node * 128);
    float4* o2 = (float4*)(out2 + (size_t)node * 128);
    o1[c]      = make_float4(a10.x * w, a10.y * w, a10.z * w, a10.w * w);
    o1[c + 16] = make_float4(a11.x * w, a11.y * w, a11.z * w, a11.w * w);
    o2[c]      = make_float4(a20.x * w, a20.y * w, a20.z * w, a20.w * w);
    o2[c + 16] = make_float4(a21.x * w, a21.y * w, a21.z * w, a21.w * w);
  }
}

// D=64 aggregate (final layer, + bias): 16 lanes/row, 4 edge slots.
__global__ __launch_bounds__(256) void aggregate64_kernel(
    const float* __restrict__ h, const float* __restrict__ gscale,
    const float* __restrict__ wscale, const float* __restrict__ bias,
    const int* __restrict__ offsets, const int* __restrict__ csr,
    float* __restrict__ out, int n) {
  int node = blockIdx.x * 4 + (threadIdx.x >> 6);
  if (node >= n) return;
  int lane = threadIdx.x & 63;
  int c = lane & 15;
  int p = lane >> 4;
  int s = offsets[node], e = offsets[node + 1];
  float4 acc = make_float4(0.f, 0.f, 0.f, 0.f);
  int i = s + p;
  for (; i + 4 < e; i += 8) {
    int sn0 = csr[i], sn1 = csr[i + 4];
    float s0 = gscale[sn0], s1 = gscale[sn1];
    float4 v0 = *((const float4*)(h + (size_t)sn0 * 64) + c);
    float4 v1 = *((const float4*)(h + (size_t)sn1 * 64) + c);
    fma4(acc, v0, s0); fma4(acc, v1, s1);
  }
  if (i < e) {
    int sn = csr[i];
    fma4(acc, *((const float4*)(h + (size_t)sn * 64) + c), gscale[sn]);
  }
#pragma unroll
  for (int off = 32; off >= 16; off >>= 1) {
    acc.x += __shfl_down(acc.x, off); acc.y += __shfl_down(acc.y, off);
    acc.z += __shfl_down(acc.z, off); acc.w += __shfl_down(acc.w, off);
  }
  if (lane < 16) {
    float w = wscale[node];
    float4 b = ((const float4*)bias)[c];
    float4 o = make_float4(acc.x * w + b.x, acc.y * w + b.y,
                           acc.z * w + b.z, acc.w * w + b.w);
    *((float4*)(out + (size_t)node * 64) + c) = o;
  }
}

// out(n x DOUT) = A(n x 128) @ W(128 x DOUT) [+ bias] [+ res] [relu]
template <int DOUT, bool RELU, bool HAS_BIAS, bool ADD_RES>
__global__ __launch_bounds__(256) void gemm_kernel(
    const float* __restrict__ A, const float* __restrict__ W,
    const float* __restrict__ bias, const float* __restrict__ res,
    float* __restrict__ out, int n) {
  __shared__ float Wl[128 * DOUT];
  __shared__ float Al[32 * 128];
  for (int i = threadIdx.x; i < 128 * DOUT / 4; i += 256)
    ((float4*)Wl)[i] = ((const float4*)W)[i];
  int row0 = blockIdx.x * 32;
  for (int i = threadIdx.x; i < 32 * 32; i += 256) {
    int r = i >> 5, cc = i & 31;
    int gr = row0 + r;
    float4 v = make_float4(0.f, 0.f, 0.f, 0.f);
    if (gr < n) v = *((const float4*)(A + (size_t)gr * 128) + cc);
    *((float4*)(Al + r * 128) + cc) = v;
  }
  __syncthreads();
  constexpr int CG = DOUT / 4;
  constexpr int RG = 256 / CG;
  constexpr int RPT = 32 / RG;
  int tc = threadIdx.x % CG;
  int tr = threadIdx.x / CG;
  float4 acc[RPT];
#pragma unroll
  for (int r = 0; r < RPT; r++) acc[r] = make_float4(0.f, 0.f, 0.f, 0.f);
  for (int k0 = 0; k0 < 128; k0 += 4) {
    float4 av[RPT];
#pragma unroll
    for (int r = 0; r < RPT; r++)
      av[r] = *((const float4*)(Al + (tr * RPT + r) * 128 + k0));
#pragma unroll
    for (int kk = 0; kk < 4; kk++) {
      float4 w = *((const float4*)(Wl + (k0 + kk) * DOUT) + tc);
#pragma unroll
      for (int r = 0; r < RPT; r++) {
        float a = (&av[r].x)[kk];
        acc[r].x += a * w.x; acc[r].y += a * w.y;
        acc[r].z += a * w.z; acc[r].w += a * w.w;
      }
    }
  }
  float4 b = make_float4(0.f, 0.f, 0.f, 0.f);
  if (HAS_BIAS) b = ((const float4*)bias)[tc];
#pragma unroll
  for (int r = 0; r < RPT; r++) {
    int gr = row0 + tr * RPT + r;
    if (gr < n) {
      float4 o = acc[r];
      o.x += b.x; o.y += b.y; o.z += b.z; o.w += b.w;
      if (ADD_RES) {
        float4 rr = *((const float4*)(res + (size_t)gr * DOUT) + tc);
        o.x += rr.x; o.y += rr.y; o.z += rr.z; o.w += rr.w;
      }
      if (RELU) {
        o.x = fmaxf(o.x, 0.f); o.y = fmaxf(o.y, 0.f);
        o.z = fmaxf(o.z, 0.f); o.w = fmaxf(o.w, 0.f);
      }
      *((float4*)(out + (size_t)gr * DOUT) + tc) = o;
    }
  }
}

extern "C" void kernel_launch(void* const* d_in, const int* in_sizes, int n_in,
                              void* d_out, int out_size, void* d_ws, size_t ws_size,
                              hipStream_t stream) {
  const float* features = (const float*)d_in[0];
  const int*   src      = (const int*)d_in[1];
  const int*   dst      = (const int*)d_in[2];
  const float* W0 = (const float*)d_in[3];
  const float* b0 = (const float*)d_in[4];
  const float* W1 = (const float*)d_in[5];
  const float* b1 = (const float*)d_in[6];
  const float* W2 = (const float*)d_in[7];
  const float* b2 = (const float*)d_in[8];
  const float* W3 = (const float*)d_in[9];
  const float* b3 = (const float*)d_in[10];
  float* out = (float*)d_out;
  const int N = GN, E = GE;

  char* ws = (char*)d_ws;
  size_t off = 0;
  auto alloc = [&](size_t bytes) -> void* {
    void* p = ws + off;
    off = (off + bytes + 255) & ~(size_t)255;
    return p;
  };
  unsigned int* partials = (unsigned int*)alloc((size_t)2 * 2 * DEG_BLOCKS * HALF_WORDS * 4);
  int*   indeg   = (int*)alloc((size_t)N * 4);
  float* innorm  = (float*)alloc((size_t)N * 4);
  float* outnorm = (float*)alloc((size_t)N * 4);
  int*   offsets = (int*)alloc((size_t)(N + 1) * 4);
  int*   cursor  = (int*)alloc((size_t)N * 4);
  int*   csr     = (int*)alloc((size_t)E * 4);
  int*   bsums   = (int*)alloc((size_t)256 * 4);
  int*   bpref   = (int*)alloc((size_t)256 * 4);
  float* res     = (float*)alloc((size_t)N * 128 * 4);
  float* bufA    = (float*)alloc((size_t)N * 128 * 4);
  float* bufB    = (float*)alloc((size_t)N * 128 * 4);
  float* Y       = (float*)alloc((size_t)N * 64 * 4);
  (void)ws_size; (void)in_sizes; (void)n_in; (void)out_size;

  // degrees + norms (no global atomics)
  degrees_lds_kernel<<<256, 256, 0, stream>>>(src, dst, partials, E);
  degrees_reduce_kernel<<<(2 * HALF_WORDS + 255) / 256, 256, 0, stream>>>(
      partials, indeg, innorm, outnorm);

  int nb = (N + SCAN_CHUNK - 1) / SCAN_CHUNK;  // 49
  scan_blocksums<<<nb, 256, 0, stream>>>(indeg, bsums, N);
  scan_bsums<<<1, 64, 0, stream>>>(bsums, bpref, nb, offsets, N);
  scan_final<<<nb, 256, 0, stream>>>(indeg, bpref, offsets, N);

  hipMemcpyAsync(cursor, offsets, (size_t)N * 4, hipMemcpyDeviceToDevice, stream);
  fill_csr_kernel<<<(E + 255) / 256, 256, 0, stream>>>(src, dst, cursor, csr, E);

  int aggGrid  = (N + 3) / 4;
  int gemmGrid = (N + 31) / 32;

  // t0 = innorm.*agg(outnorm.*f); res = innorm.*agg(innorm.*f) — one gather pass
  aggregate_dual_kernel<<<aggGrid, 256, 0, stream>>>(
      features, outnorm, innorm, innorm, offsets, csr, bufA, res, N);
  // h0 = relu(t0 @ W0 + b0)
  gemm_kernel<128, true, true, false><<<gemmGrid, 256, 0, stream>>>(
      bufA, W0, b0, nullptr, bufB, N);
  // t1 = innorm .* agg(outnorm .* h0)
  aggregate128_kernel<<<aggGrid, 256, 0, stream>>>(
      bufB, outnorm, innorm, offsets, csr, bufA, N);
  // h1 = relu(t1 @ W1 + b1 + res)
  gemm_kernel<128, true, true, true><<<gemmGrid, 256, 0, stream>>>(
      bufA, W1, b1, res, bufB, N);
  // t2 = innorm .* agg(outnorm .* h1)
  aggregate128_kernel<<<aggGrid, 256, 0, stream>>>(
      bufB, outnorm, innorm, offsets, csr, bufA, N);
  // h2 = relu(t2 @ W2 + b2 + res)
  gemm_kernel<128, true, true, true><<<gemmGrid, 256, 0, stream>>>(
      bufA, W2, b2, res, bufB, N);
  // Y = h2 @ W3  (matmul commutes with aggregation; 64-wide aggregate after)
  gemm_kernel<64, false, false, false><<<gemmGrid, 256, 0, stream>>>(
      bufB, W3, nullptr, nullptr, Y, N);
  // out = innorm .* agg(outnorm .* Y) + b3
  aggregate64_kernel<<<aggGrid, 256, 0, stream>>>(
      Y, outnorm, innorm, b3, offsets, csr, out, N);
}

// Round 5
// 428.451 us; speedup vs baseline: 1.6676x; 1.1827x over previous
//
#include <hip/hip_runtime.h>

// GResNet GCN: N=50000, E=800000, d=128 (out 64).
// R5 changes:
//  (1) all aggregate gather sources stored packed bf16 (rows 256B/128B) ->
//      gather fill traffic halves; unpack = shift-into-high-bits (free-ish).
//      GEMM A/accum/res stay fp32.
//  (2) fill_csr via LDS counting sort reusing degree partials (no global
//      atomics; degrees_reduce also emits per-slice exclusive prefix rel16).
//  (3) buffer aliasing: fbf16 aliases bufB, Ybf aliases res.

#define GN 50000
#define GE 800000
#define SCAN_CHUNK 1024
#define DEG_BLOCKS 64
#define DEG_SLICE 12500      // GE / DEG_BLOCKS
#define HALF_NODES 25000
#define HALF_WORDS 12500     // packed uint16 pairs

__device__ __forceinline__ float u2f(unsigned int u) { return __uint_as_float(u); }

__device__ __forceinline__ unsigned int bfpack(float a, float b) {
  unsigned int ua = __float_as_uint(a); ua = (ua + 0x7fffu + ((ua >> 16) & 1u)) >> 16;
  unsigned int ub = __float_as_uint(b); ub = (ub + 0x7fffu + ((ub >> 16) & 1u)) >> 16;
  return ua | (ub << 16);
}

// unpack uint4 (8 bf16) -> 8 floats
__device__ __forceinline__ void bfunpack8(uint4 u, float* f) {
  f[0] = u2f(u.x << 16); f[1] = u2f(u.x & 0xffff0000u);
  f[2] = u2f(u.y << 16); f[3] = u2f(u.y & 0xffff0000u);
  f[4] = u2f(u.z << 16); f[5] = u2f(u.z & 0xffff0000u);
  f[6] = u2f(u.w << 16); f[7] = u2f(u.w & 0xffff0000u);
}

// ---- degrees via LDS histograms ----
// blockIdx: b = bits[0:6) edge slice, half = bit 6, dir = bit 7 (0=dst/in, 1=src/out)
__global__ __launch_bounds__(256) void degrees_lds_kernel(
    const int* __restrict__ src, const int* __restrict__ dst,
    unsigned int* __restrict__ partials, int E) {
  __shared__ unsigned int hist[HALF_WORDS];
  for (int i = threadIdx.x; i < HALF_WORDS; i += 256) hist[i] = 0u;
  __syncthreads();
  int b    = blockIdx.x & 63;
  int half = (blockIdx.x >> 6) & 1;
  int dir  = blockIdx.x >> 7;
  const int* __restrict__ idx = dir ? src : dst;
  int lo = half * HALF_NODES, hi = lo + HALF_NODES;
  int s = b * DEG_SLICE;
  int e = min(s + DEG_SLICE, E);
  for (int i = s + threadIdx.x; i < e; i += 256) {
    int node = idx[i];
    if (node >= lo && node < hi) {
      int local = node - lo;
      atomicAdd(&hist[local >> 1], 1u << ((local & 1) << 4));
    }
  }
  __syncthreads();
  unsigned int* outp = partials + (((size_t)dir * 2 + half) * DEG_BLOCKS + b) * HALF_WORDS;
  for (int i = threadIdx.x; i < HALF_WORDS; i += 256) outp[i] = hist[i];
}

// Reduce partials -> indeg/norms, and emit rel16[b][node] = exclusive prefix of
// per-slice in-counts (uint16, packed pair-write).
__global__ void degrees_reduce_kernel(const unsigned int* __restrict__ partials,
                                      int* __restrict__ indeg, float* __restrict__ innorm,
                                      float* __restrict__ outnorm,
                                      unsigned int* __restrict__ rel16pk) {
  int g = blockIdx.x * blockDim.x + threadIdx.x;   // [0, 2*HALF_WORDS)
  if (g >= 2 * HALF_WORDS) return;
  int half = (g >= HALF_WORDS) ? 1 : 0;
  int w = g - half * HALF_WORDS;
  int n0 = half * HALF_NODES + 2 * w;              // even
  unsigned int inLo = 0, inHi = 0, outLo = 0, outHi = 0;
  const unsigned int* pIn  = partials + ((size_t)(0 * 2 + half) * DEG_BLOCKS) * HALF_WORDS + w;
  const unsigned int* pOut = partials + ((size_t)(1 * 2 + half) * DEG_BLOCKS) * HALF_WORDS + w;
#pragma unroll 4
  for (int b = 0; b < DEG_BLOCKS; b++) {
    // write exclusive prefix BEFORE adding this slice's counts
    rel16pk[((size_t)b * GN + n0) >> 1] = inLo | (inHi << 16);
    unsigned int v = pIn[(size_t)b * HALF_WORDS];
    inLo += v & 0xffffu; inHi += v >> 16;
    unsigned int u = pOut[(size_t)b * HALF_WORDS];
    outLo += u & 0xffffu; outHi += u >> 16;
  }
  indeg[n0]     = (int)inLo;
  indeg[n0 + 1] = (int)inHi;
  innorm[n0]      = rsqrtf((float)max((int)inLo, 1));
  innorm[n0 + 1]  = rsqrtf((float)max((int)inHi, 1));
  outnorm[n0]     = rsqrtf((float)max((int)outLo, 1));
  outnorm[n0 + 1] = rsqrtf((float)max((int)outHi, 1));
}

// ---- hierarchical scan over indeg -> offsets ----
__global__ __launch_bounds__(256) void scan_blocksums(const int* __restrict__ deg,
                                                      int* __restrict__ bsums, int n) {
  int tid = threadIdx.x;
  int i = blockIdx.x * SCAN_CHUNK + tid * 4;
  int s = 0;
  if (i + 3 < n) {
    int4 v = *(const int4*)(deg + i);
    s = v.x + v.y + v.z + v.w;
  } else {
    for (int j = 0; j < 4; j++) if (i + j < n) s += deg[i + j];
  }
  for (int off = 32; off; off >>= 1) s += __shfl_down(s, off);
  __shared__ int ws[4];
  if ((tid & 63) == 0) ws[tid >> 6] = s;
  __syncthreads();
  if (tid == 0) bsums[blockIdx.x] = ws[0] + ws[1] + ws[2] + ws[3];
}

__global__ void scan_bsums(const int* __restrict__ bsums, int* __restrict__ bpref,
                           int nb, int* __restrict__ offsets, int n) {
  int tid = threadIdx.x;
  int v = (tid < nb) ? bsums[tid] : 0;
  int incl = v;
  for (int off = 1; off < 64; off <<= 1) {
    int t = __shfl_up(incl, off);
    if (tid >= off) incl += t;
  }
  if (tid < nb) bpref[tid] = incl - v;
  if (tid == 63) offsets[n] = incl;
}

__global__ __launch_bounds__(256) void scan_final(const int* __restrict__ deg,
                                                  const int* __restrict__ bpref,
                                                  int* __restrict__ offsets, int n) {
  int tid = threadIdx.x;
  int i = blockIdx.x * SCAN_CHUNK + tid * 4;
  int v[4];
#pragma unroll
  for (int j = 0; j < 4; j++) v[j] = (i + j < n) ? deg[i + j] : 0;
  int tsum = v[0] + v[1] + v[2] + v[3];
  int incl = tsum;
  for (int off = 1; off < 64; off <<= 1) {
    int t = __shfl_up(incl, off);
    if ((tid & 63) >= off) incl += t;
  }
  __shared__ int wsum[4];
  int wid = tid >> 6, lane = tid & 63;
  if (lane == 63) wsum[wid] = incl;
  __syncthreads();
  int wpref = 0;
  for (int w = 0; w < wid; w++) wpref += wsum[w];
  int run = bpref[blockIdx.x] + wpref + incl - tsum;
#pragma unroll
  for (int j = 0; j < 4; j++) {
    if (i + j < n) offsets[i + j] = run;
    run += v[j];
  }
}

// ---- CSR fill via LDS counting sort (no global atomics) ----
// blockIdx: b = bits[0:6) slice, half = bit 6. rank from packed LDS atomicAdd.
__global__ __launch_bounds__(256) void fill_csr_lds_kernel(
    const int* __restrict__ src, const int* __restrict__ dst,
    const int* __restrict__ offsets, const unsigned short* __restrict__ rel16,
    int* __restrict__ csr, int E) {
  __shared__ unsigned int cnt[HALF_WORDS];
  for (int i = threadIdx.x; i < HALF_WORDS; i += 256) cnt[i] = 0u;
  __syncthreads();
  int b    = blockIdx.x & 63;
  int half = blockIdx.x >> 6;
  int lo = half * HALF_NODES, hi = lo + HALF_NODES;
  int s = b * DEG_SLICE;
  int e = min(s + DEG_SLICE, E);
  const unsigned short* relb = rel16 + (size_t)b * GN;
  for (int i = s + threadIdx.x; i < e; i += 256) {
    int d = dst[i];
    if (d >= lo && d < hi) {
      int local = d - lo;
      int sh = (local & 1) << 4;
      unsigned int old = atomicAdd(&cnt[local >> 1], 1u << sh);
      int rank = (int)((old >> sh) & 0xffffu);
      int pos = offsets[d] + (int)relb[d] + rank;
      csr[pos] = src[i];
    }
  }
}

// ---- feature fp32 -> packed bf16 ----
__global__ __launch_bounds__(256) void f32_to_bf16_kernel(const float* __restrict__ in,
                                                          uint4* __restrict__ out, int n8) {
  int t = blockIdx.x * blockDim.x + threadIdx.x;
  if (t >= n8) return;
  const float4* in4 = (const float4*)in;
  float4 f0 = in4[2 * t], f1 = in4[2 * t + 1];
  uint4 o;
  o.x = bfpack(f0.x, f0.y); o.y = bfpack(f0.z, f0.w);
  o.z = bfpack(f1.x, f1.y); o.w = bfpack(f1.z, f1.w);
  out[t] = o;
}

// ---- aggregates over packed-bf16 rows ----
// D=128: rows are 16 uint4; 16 lanes/row, 4 edge slots, x2 unroll.
__global__ __launch_bounds__(256) void aggregate128_bf16_kernel(
    const uint4* __restrict__ hq, const float* __restrict__ gscale,
    const float* __restrict__ wscale, const int* __restrict__ offsets,
    const int* __restrict__ csr, float* __restrict__ out, int n) {
  int node = blockIdx.x * 4 + (threadIdx.x >> 6);
  if (node >= n) return;
  int lane = threadIdx.x & 63;
  int c = lane & 15;
  int p = lane >> 4;
  int s = offsets[node], e = offsets[node + 1];
  float acc[8];
#pragma unroll
  for (int j = 0; j < 8; j++) acc[j] = 0.f;
  int i = s + p;
  for (; i + 4 < e; i += 8) {
    int sn0 = csr[i], sn1 = csr[i + 4];
    uint4 u0 = hq[(size_t)sn0 * 16 + c];
    uint4 u1 = hq[(size_t)sn1 * 16 + c];
    float s0 = gscale[sn0], s1 = gscale[sn1];
    float f0[8], f1[8];
    bfunpack8(u0, f0); bfunpack8(u1, f1);
#pragma unroll
    for (int j = 0; j < 8; j++) acc[j] += f0[j] * s0 + f1[j] * s1;
  }
  if (i < e) {
    int sn = csr[i];
    uint4 u = hq[(size_t)sn * 16 + c];
    float sc = gscale[sn];
    float f[8];
    bfunpack8(u, f);
#pragma unroll
    for (int j = 0; j < 8; j++) acc[j] += f[j] * sc;
  }
#pragma unroll
  for (int off = 32; off >= 16; off >>= 1)
#pragma unroll
    for (int j = 0; j < 8; j++) acc[j] += __shfl_down(acc[j], off);
  if (lane < 16) {
    float w = wscale[node];
    float4* orow = (float4*)(out + (size_t)node * 128);
    orow[2 * c]     = make_float4(acc[0] * w, acc[1] * w, acc[2] * w, acc[3] * w);
    orow[2 * c + 1] = make_float4(acc[4] * w, acc[5] * w, acc[6] * w, acc[7] * w);
  }
}

// Dual: out1 = w.*agg(g1.*h), out2 = w.*agg(g2.*h), one bf16 gather pass.
__global__ __launch_bounds__(256) void aggregate_dual_bf16_kernel(
    const uint4* __restrict__ hq, const float* __restrict__ g1,
    const float* __restrict__ g2, const float* __restrict__ wscale,
    const int* __restrict__ offsets, const int* __restrict__ csr,
    float* __restrict__ out1, float* __restrict__ out2, int n) {
  int node = blockIdx.x * 4 + (threadIdx.x >> 6);
  if (node >= n) return;
  int lane = threadIdx.x & 63;
  int c = lane & 15;
  int p = lane >> 4;
  int s = offsets[node], e = offsets[node + 1];
  float a1[8], a2[8];
#pragma unroll
  for (int j = 0; j < 8; j++) { a1[j] = 0.f; a2[j] = 0.f; }
  int i = s + p;
  for (; i + 4 < e; i += 8) {
    int sn0 = csr[i], sn1 = csr[i + 4];
    uint4 u0 = hq[(size_t)sn0 * 16 + c];
    uint4 u1 = hq[(size_t)sn1 * 16 + c];
    float g1a = g1[sn0], g2a = g2[sn0];
    float g1b = g1[sn1], g2b = g2[sn1];
    float f0[8], f1[8];
    bfunpack8(u0, f0); bfunpack8(u1, f1);
#pragma unroll
    for (int j = 0; j < 8; j++) {
      a1[j] += f0[j] * g1a + f1[j] * g1b;
      a2[j] += f0[j] * g2a + f1[j] * g2b;
    }
  }
  if (i < e) {
    int sn = csr[i];
    uint4 u = hq[(size_t)sn * 16 + c];
    float g1a = g1[sn], g2a = g2[sn];
    float f[8];
    bfunpack8(u, f);
#pragma unroll
    for (int j = 0; j < 8; j++) { a1[j] += f[j] * g1a; a2[j] += f[j] * g2a; }
  }
#pragma unroll
  for (int off = 32; off >= 16; off >>= 1)
#pragma unroll
    for (int j = 0; j < 8; j++) {
      a1[j] += __shfl_down(a1[j], off);
      a2[j] += __shfl_down(a2[j], off);
    }
  if (lane < 16) {
    float w = wscale[node];
    float4* o1 = (float4*)(out1 + (size_t)node * 128);
    float4* o2 = (float4*)(out2 + (size_t)node * 128);
    o1[2 * c]     = make_float4(a1[0] * w, a1[1] * w, a1[2] * w, a1[3] * w);
    o1[2 * c + 1] = make_float4(a1[4] * w, a1[5] * w, a1[6] * w, a1[7] * w);
    o2[2 * c]     = make_float4(a2[0] * w, a2[1] * w, a2[2] * w, a2[3] * w);
    o2[2 * c + 1] = make_float4(a2[4] * w, a2[5] * w, a2[6] * w, a2[7] * w);
  }
}

// D=64 (final, + bias): rows are 8 uint4; 8 lanes/row, 8 slots, x2 unroll.
__global__ __launch_bounds__(256) void aggregate64_bf16_kernel(
    const uint4* __restrict__ hq, const float* __restrict__ gscale,
    const float* __restrict__ wscale, const float* __restrict__ bias,
    const int* __restrict__ offsets, const int* __restrict__ csr,
    float* __restrict__ out, int n) {
  int node = blockIdx.x * 4 + (threadIdx.x >> 6);
  if (node >= n) return;
  int lane = threadIdx.x & 63;
  int c = lane & 7;
  int p = lane >> 3;
  int s = offsets[node], e = offsets[node + 1];
  float acc[8];
#pragma unroll
  for (int j = 0; j < 8; j++) acc[j] = 0.f;
  int i = s + p;
  for (; i + 8 < e; i += 16) {
    int sn0 = csr[i], sn1 = csr[i + 8];
    uint4 u0 = hq[(size_t)sn0 * 8 + c];
    uint4 u1 = hq[(size_t)sn1 * 8 + c];
    float s0 = gscale[sn0], s1 = gscale[sn1];
    float f0[8], f1[8];
    bfunpack8(u0, f0); bfunpack8(u1, f1);
#pragma unroll
    for (int j = 0; j < 8; j++) acc[j] += f0[j] * s0 + f1[j] * s1;
  }
  if (i < e) {
    int sn = csr[i];
    uint4 u = hq[(size_t)sn * 8 + c];
    float sc = gscale[sn];
    float f[8];
    bfunpack8(u, f);
#pragma unroll
    for (int j = 0; j < 8; j++) acc[j] += f[j] * sc;
  }
#pragma unroll
  for (int off = 32; off >= 8; off >>= 1)
#pragma unroll
    for (int j = 0; j < 8; j++) acc[j] += __shfl_down(acc[j], off);
  if (lane < 8) {
    float w = wscale[node];
    const float4* bp = (const float4*)bias;
    float4 b0 = bp[2 * c], b1 = bp[2 * c + 1];
    float4* orow = (float4*)(out + (size_t)node * 64);
    orow[2 * c]     = make_float4(acc[0] * w + b0.x, acc[1] * w + b0.y,
                                  acc[2] * w + b0.z, acc[3] * w + b0.w);
    orow[2 * c + 1] = make_float4(acc[4] * w + b1.x, acc[5] * w + b1.y,
                                  acc[6] * w + b1.z, acc[7] * w + b1.w);
  }
}

// out(n x DOUT) = A(n x 128) @ W(128 x DOUT) [+ bias] [+ res] [relu]
// OUT_BF16: epilogue packs pairs to bf16 (for gather-only consumers).
template <int DOUT, bool RELU, bool HAS_BIAS, bool ADD_RES, bool OUT_BF16>
__global__ __launch_bounds__(256) void gemm_kernel(
    const float* __restrict__ A, const float* __restrict__ W,
    const float* __restrict__ bias, const float* __restrict__ res,
    void* __restrict__ outv, int n) {
  __shared__ float Wl[128 * DOUT];
  __shared__ float Al[32 * 128];
  for (int i = threadIdx.x; i < 128 * DOUT / 4; i += 256)
    ((float4*)Wl)[i] = ((const float4*)W)[i];
  int row0 = blockIdx.x * 32;
  for (int i = threadIdx.x; i < 32 * 32; i += 256) {
    int r = i >> 5, cc = i & 31;
    int gr = row0 + r;
    float4 v = make_float4(0.f, 0.f, 0.f, 0.f);
    if (gr < n) v = *((const float4*)(A + (size_t)gr * 128) + cc);
    *((float4*)(Al + r * 128) + cc) = v;
  }
  __syncthreads();
  constexpr int CG = DOUT / 4;
  constexpr int RG = 256 / CG;
  constexpr int RPT = 32 / RG;
  int tc = threadIdx.x % CG;
  int tr = threadIdx.x / CG;
  float4 acc[RPT];
#pragma unroll
  for (int r = 0; r < RPT; r++) acc[r] = make_float4(0.f, 0.f, 0.f, 0.f);
  for (int k0 = 0; k0 < 128; k0 += 4) {
    float4 av[RPT];
#pragma unroll
    for (int r = 0; r < RPT; r++)
      av[r] = *((const float4*)(Al + (tr * RPT + r) * 128 + k0));
#pragma unroll
    for (int kk = 0; kk < 4; kk++) {
      float4 w = *((const float4*)(Wl + (k0 + kk) * DOUT) + tc);
#pragma unroll
      for (int r = 0; r < RPT; r++) {
        float a = (&av[r].x)[kk];
        acc[r].x += a * w.x; acc[r].y += a * w.y;
        acc[r].z += a * w.z; acc[r].w += a * w.w;
      }
    }
  }
  float4 b = make_float4(0.f, 0.f, 0.f, 0.f);
  if (HAS_BIAS) b = ((const float4*)bias)[tc];
#pragma unroll
  for (int r = 0; r < RPT; r++) {
    int gr = row0 + tr * RPT + r;
    if (gr < n) {
      float4 o = acc[r];
      o.x += b.x; o.y += b.y; o.z += b.z; o.w += b.w;
      if (ADD_RES) {
        float4 rr = *((const float4*)(res + (size_t)gr * DOUT) + tc);
        o.x += rr.x; o.y += rr.y; o.z += rr.z; o.w += rr.w;
      }
      if (RELU) {
        o.x = fmaxf(o.x, 0.f); o.y = fmaxf(o.y, 0.f);
        o.z = fmaxf(o.z, 0.f); o.w = fmaxf(o.w, 0.f);
      }
      if (OUT_BF16) {
        uint2 pk;
        pk.x = bfpack(o.x, o.y); pk.y = bfpack(o.z, o.w);
        unsigned int* up = (unsigned int*)outv;
        *(uint2*)(up + (size_t)gr * (DOUT / 2) + tc * 2) = pk;
      } else {
        float* outp = (float*)outv;
        *((float4*)(outp + (size_t)gr * DOUT) + tc) = o;
      }
    }
  }
}

extern "C" void kernel_launch(void* const* d_in, const int* in_sizes, int n_in,
                              void* d_out, int out_size, void* d_ws, size_t ws_size,
                              hipStream_t stream) {
  const float* features = (const float*)d_in[0];
  const int*   src      = (const int*)d_in[1];
  const int*   dst      = (const int*)d_in[2];
  const float* W0 = (const float*)d_in[3];
  const float* b0 = (const float*)d_in[4];
  const float* W1 = (const float*)d_in[5];
  const float* b1 = (const float*)d_in[6];
  const float* W2 = (const float*)d_in[7];
  const float* b2 = (const float*)d_in[8];
  const float* W3 = (const float*)d_in[9];
  const float* b3 = (const float*)d_in[10];
  float* out = (float*)d_out;
  const int N = GN, E = GE;

  char* ws = (char*)d_ws;
  size_t off = 0;
  auto alloc = [&](size_t bytes) -> void* {
    void* p = ws + off;
    off = (off + bytes + 255) & ~(size_t)255;
    return p;
  };
  unsigned int* partials = (unsigned int*)alloc((size_t)2 * 2 * DEG_BLOCKS * HALF_WORDS * 4);
  unsigned int* rel16pk  = (unsigned int*)alloc((size_t)DEG_BLOCKS * GN * 2);  // uint16[64][N]
  int*   indeg   = (int*)alloc((size_t)N * 4);
  float* innorm  = (float*)alloc((size_t)N * 4);
  float* outnorm = (float*)alloc((size_t)N * 4);
  int*   offsets = (int*)alloc((size_t)(N + 1) * 4);
  int*   csr     = (int*)alloc((size_t)E * 4);
  int*   bsums   = (int*)alloc((size_t)256 * 4);
  int*   bpref   = (int*)alloc((size_t)256 * 4);
  float* res     = (float*)alloc((size_t)N * 128 * 4);   // also hosts Ybf later
  float* bufA    = (float*)alloc((size_t)N * 128 * 4);
  float* bufB    = (float*)alloc((size_t)N * 128 * 4);   // fbf16 early, h2 fp32 late
  uint4* hbf     = (uint4*)alloc((size_t)N * 128 * 2);   // h0/h1 packed bf16
  (void)ws_size; (void)in_sizes; (void)n_in; (void)out_size;

  uint4* fbf = (uint4*)bufB;              // features bf16 (dead before h2 written)
  uint4* Ybf = (uint4*)res;               // Y bf16 (dead after gemm W2 reads res)

  // degrees + norms + per-slice prefix (no global atomics)
  degrees_lds_kernel<<<256, 256, 0, stream>>>(src, dst, partials, E);
  degrees_reduce_kernel<<<(2 * HALF_WORDS + 255) / 256, 256, 0, stream>>>(
      partials, indeg, innorm, outnorm, rel16pk);

  int nb = (N + SCAN_CHUNK - 1) / SCAN_CHUNK;  // 49
  scan_blocksums<<<nb, 256, 0, stream>>>(indeg, bsums, N);
  scan_bsums<<<1, 64, 0, stream>>>(bsums, bpref, nb, offsets, N);
  scan_final<<<nb, 256, 0, stream>>>(indeg, bpref, offsets, N);

  // CSR fill via LDS counting sort
  fill_csr_lds_kernel<<<128, 256, 0, stream>>>(
      src, dst, offsets, (const unsigned short*)rel16pk, csr, E);

  // features -> packed bf16
  f32_to_bf16_kernel<<<(N * 128 / 8 + 255) / 256, 256, 0, stream>>>(
      features, fbf, N * 128 / 8);

  int aggGrid  = (N + 3) / 4;
  int gemmGrid = (N + 31) / 32;

  // t0 = innorm.*agg(outnorm.*f); res = innorm.*agg(innorm.*f) — one gather pass
  aggregate_dual_bf16_kernel<<<aggGrid, 256, 0, stream>>>(
      fbf, outnorm, innorm, innorm, offsets, csr, bufA, res, N);
  // h0 = relu(t0 @ W0 + b0)  -> bf16
  gemm_kernel<128, true, true, false, true><<<gemmGrid, 256, 0, stream>>>(
      bufA, W0, b0, nullptr, hbf, N);
  // t1 = innorm .* agg(outnorm .* h0)
  aggregate128_bf16_kernel<<<aggGrid, 256, 0, stream>>>(
      hbf, outnorm, innorm, offsets, csr, bufA, N);
  // h1 = relu(t1 @ W1 + b1 + res) -> bf16 (overwrites h0, dead)
  gemm_kernel<128, true, true, true, true><<<gemmGrid, 256, 0, stream>>>(
      bufA, W1, b1, res, hbf, N);
  // t2 = innorm .* agg(outnorm .* h1)
  aggregate128_bf16_kernel<<<aggGrid, 256, 0, stream>>>(
      hbf, outnorm, innorm, offsets, csr, bufA, N);
  // h2 = relu(t2 @ W2 + b2 + res) -> fp32 (consumed only by W3 GEMM)
  gemm_kernel<128, true, true, true, false><<<gemmGrid, 256, 0, stream>>>(
      bufA, W2, b2, res, bufB, N);
  // Y = h2 @ W3 -> bf16 (res is dead now; Ybf aliases it)
  gemm_kernel<64, false, false, false, true><<<gemmGrid, 256, 0, stream>>>(
      bufB, W3, nullptr, nullptr, Ybf, N);
  // out = innorm .* agg(outnorm .* Y) + b3
  aggregate64_bf16_kernel<<<aggGrid, 256, 0, stream>>>(
      Ybf, outnorm, innorm, b3, offsets, csr, out, N);
}

// Round 6
// 385.263 us; speedup vs baseline: 1.8546x; 1.1121x over previous
//
#include <hip/hip_runtime.h>

// GResNet GCN: N=50000, E=800000, d=128 (out 64).
// R6 change: replace fp32 VALU GEMM (50us each, 16% occupancy, 80KB LDS) with
// MFMA bf16 GEMM, zero LDS, W pre-split hi/lo (transposed) so W error ~2^-17.
// Aggregates now emit bf16 outputs (GEMM A operands) directly.

#define GN 50000
#define GE 800000
#define SCAN_CHUNK 1024
#define DEG_BLOCKS 64
#define DEG_SLICE 12500      // GE / DEG_BLOCKS
#define HALF_NODES 25000
#define HALF_WORDS 12500     // packed uint16 pairs

typedef __attribute__((ext_vector_type(8))) short bf16x8;
typedef __attribute__((ext_vector_type(4))) float f32x4;

__device__ __forceinline__ float u2f(unsigned int u) { return __uint_as_float(u); }

__device__ __forceinline__ unsigned int bfr(float a) {   // fp32 -> bf16 bits (RNE)
  unsigned int u = __float_as_uint(a);
  return (u + 0x7fffu + ((u >> 16) & 1u)) >> 16;
}
__device__ __forceinline__ unsigned int bfpack(float a, float b) {
  return bfr(a) | (bfr(b) << 16);
}
__device__ __forceinline__ void bfunpack8(uint4 u, float* f) {
  f[0] = u2f(u.x << 16); f[1] = u2f(u.x & 0xffff0000u);
  f[2] = u2f(u.y << 16); f[3] = u2f(u.y & 0xffff0000u);
  f[4] = u2f(u.z << 16); f[5] = u2f(u.z & 0xffff0000u);
  f[6] = u2f(u.w << 16); f[7] = u2f(u.w & 0xffff0000u);
}

// ---- degrees via LDS histograms ----
__global__ __launch_bounds__(256) void degrees_lds_kernel(
    const int* __restrict__ src, const int* __restrict__ dst,
    unsigned int* __restrict__ partials, int E) {
  __shared__ unsigned int hist[HALF_WORDS];
  for (int i = threadIdx.x; i < HALF_WORDS; i += 256) hist[i] = 0u;
  __syncthreads();
  int b    = blockIdx.x & 63;
  int half = (blockIdx.x >> 6) & 1;
  int dir  = blockIdx.x >> 7;
  const int* __restrict__ idx = dir ? src : dst;
  int lo = half * HALF_NODES, hi = lo + HALF_NODES;
  int s = b * DEG_SLICE;
  int e = min(s + DEG_SLICE, E);
  for (int i = s + threadIdx.x; i < e; i += 256) {
    int node = idx[i];
    if (node >= lo && node < hi) {
      int local = node - lo;
      atomicAdd(&hist[local >> 1], 1u << ((local & 1) << 4));
    }
  }
  __syncthreads();
  unsigned int* outp = partials + (((size_t)dir * 2 + half) * DEG_BLOCKS + b) * HALF_WORDS;
  for (int i = threadIdx.x; i < HALF_WORDS; i += 256) outp[i] = hist[i];
}

__global__ void degrees_reduce_kernel(const unsigned int* __restrict__ partials,
                                      int* __restrict__ indeg, float* __restrict__ innorm,
                                      float* __restrict__ outnorm,
                                      unsigned int* __restrict__ rel16pk) {
  int g = blockIdx.x * blockDim.x + threadIdx.x;
  if (g >= 2 * HALF_WORDS) return;
  int half = (g >= HALF_WORDS) ? 1 : 0;
  int w = g - half * HALF_WORDS;
  int n0 = half * HALF_NODES + 2 * w;
  unsigned int inLo = 0, inHi = 0, outLo = 0, outHi = 0;
  const unsigned int* pIn  = partials + ((size_t)(0 * 2 + half) * DEG_BLOCKS) * HALF_WORDS + w;
  const unsigned int* pOut = partials + ((size_t)(1 * 2 + half) * DEG_BLOCKS) * HALF_WORDS + w;
#pragma unroll 4
  for (int b = 0; b < DEG_BLOCKS; b++) {
    rel16pk[((size_t)b * GN + n0) >> 1] = inLo | (inHi << 16);
    unsigned int v = pIn[(size_t)b * HALF_WORDS];
    inLo += v & 0xffffu; inHi += v >> 16;
    unsigned int u = pOut[(size_t)b * HALF_WORDS];
    outLo += u & 0xffffu; outHi += u >> 16;
  }
  indeg[n0]     = (int)inLo;
  indeg[n0 + 1] = (int)inHi;
  innorm[n0]      = rsqrtf((float)max((int)inLo, 1));
  innorm[n0 + 1]  = rsqrtf((float)max((int)inHi, 1));
  outnorm[n0]     = rsqrtf((float)max((int)outLo, 1));
  outnorm[n0 + 1] = rsqrtf((float)max((int)outHi, 1));
}

// ---- hierarchical scan over indeg -> offsets ----
__global__ __launch_bounds__(256) void scan_blocksums(const int* __restrict__ deg,
                                                      int* __restrict__ bsums, int n) {
  int tid = threadIdx.x;
  int i = blockIdx.x * SCAN_CHUNK + tid * 4;
  int s = 0;
  if (i + 3 < n) {
    int4 v = *(const int4*)(deg + i);
    s = v.x + v.y + v.z + v.w;
  } else {
    for (int j = 0; j < 4; j++) if (i + j < n) s += deg[i + j];
  }
  for (int off = 32; off; off >>= 1) s += __shfl_down(s, off);
  __shared__ int ws[4];
  if ((tid & 63) == 0) ws[tid >> 6] = s;
  __syncthreads();
  if (tid == 0) bsums[blockIdx.x] = ws[0] + ws[1] + ws[2] + ws[3];
}

__global__ void scan_bsums(const int* __restrict__ bsums, int* __restrict__ bpref,
                           int nb, int* __restrict__ offsets, int n) {
  int tid = threadIdx.x;
  int v = (tid < nb) ? bsums[tid] : 0;
  int incl = v;
  for (int off = 1; off < 64; off <<= 1) {
    int t = __shfl_up(incl, off);
    if (tid >= off) incl += t;
  }
  if (tid < nb) bpref[tid] = incl - v;
  if (tid == 63) offsets[n] = incl;
}

__global__ __launch_bounds__(256) void scan_final(const int* __restrict__ deg,
                                                  const int* __restrict__ bpref,
                                                  int* __restrict__ offsets, int n) {
  int tid = threadIdx.x;
  int i = blockIdx.x * SCAN_CHUNK + tid * 4;
  int v[4];
#pragma unroll
  for (int j = 0; j < 4; j++) v[j] = (i + j < n) ? deg[i + j] : 0;
  int tsum = v[0] + v[1] + v[2] + v[3];
  int incl = tsum;
  for (int off = 1; off < 64; off <<= 1) {
    int t = __shfl_up(incl, off);
    if ((tid & 63) >= off) incl += t;
  }
  __shared__ int wsum[4];
  int wid = tid >> 6, lane = tid & 63;
  if (lane == 63) wsum[wid] = incl;
  __syncthreads();
  int wpref = 0;
  for (int w = 0; w < wid; w++) wpref += wsum[w];
  int run = bpref[blockIdx.x] + wpref + incl - tsum;
#pragma unroll
  for (int j = 0; j < 4; j++) {
    if (i + j < n) offsets[i + j] = run;
    run += v[j];
  }
}

// ---- CSR fill via LDS counting sort ----
__global__ __launch_bounds__(256) void fill_csr_lds_kernel(
    const int* __restrict__ src, const int* __restrict__ dst,
    const int* __restrict__ offsets, const unsigned short* __restrict__ rel16,
    int* __restrict__ csr, int E) {
  __shared__ unsigned int cnt[HALF_WORDS];
  for (int i = threadIdx.x; i < HALF_WORDS; i += 256) cnt[i] = 0u;
  __syncthreads();
  int b    = blockIdx.x & 63;
  int half = blockIdx.x >> 6;
  int lo = half * HALF_NODES, hi = lo + HALF_NODES;
  int s = b * DEG_SLICE;
  int e = min(s + DEG_SLICE, E);
  const unsigned short* relb = rel16 + (size_t)b * GN;
  for (int i = s + threadIdx.x; i < e; i += 256) {
    int d = dst[i];
    if (d >= lo && d < hi) {
      int local = d - lo;
      int sh = (local & 1) << 4;
      unsigned int old = atomicAdd(&cnt[local >> 1], 1u << sh);
      int rank = (int)((old >> sh) & 0xffffu);
      int pos = offsets[d] + (int)relb[d] + rank;
      csr[pos] = src[i];
    }
  }
}

// ---- feature fp32 -> packed bf16 ----
__global__ __launch_bounds__(256) void f32_to_bf16_kernel(const float* __restrict__ in,
                                                          uint4* __restrict__ out, int n8) {
  int t = blockIdx.x * blockDim.x + threadIdx.x;
  if (t >= n8) return;
  const float4* in4 = (const float4*)in;
  float4 f0 = in4[2 * t], f1 = in4[2 * t + 1];
  uint4 o;
  o.x = bfpack(f0.x, f0.y); o.y = bfpack(f0.z, f0.w);
  o.z = bfpack(f1.x, f1.y); o.w = bfpack(f1.z, f1.w);
  out[t] = o;
}

// ---- W -> transposed bf16 hi/lo planes ----
// wt layout (ushorts): W0h@0 W0l@16384 W1h@32768 W1l@49152 W2h@65536 W2l@81920
//                      W3h@98304 W3l@106496. All planes [N][128].
__global__ __launch_bounds__(256) void wconvert_kernel(
    const float* __restrict__ W0, const float* __restrict__ W1,
    const float* __restrict__ W2, const float* __restrict__ W3,
    unsigned short* __restrict__ wt) {
  int e = blockIdx.x * 256 + threadIdx.x;
  if (e >= 3 * 16384 + 8192) return;
  int m, local, N;
  if (e < 49152) { m = e >> 14; local = e & 16383; N = 128; }
  else { m = 3; local = e - 49152; N = 64; }
  const float* W = (m == 0) ? W0 : (m == 1) ? W1 : (m == 2) ? W2 : W3;
  int k = local / N, n = local % N;
  float v = W[k * N + n];
  unsigned int hi = bfr(v);
  float rem = v - u2f(hi << 16);
  unsigned int lo = bfr(rem);
  size_t hibase = (m < 3) ? (size_t)m * 32768 : 98304;
  size_t lobase = hibase + ((m < 3) ? 16384 : 8192);
  wt[hibase + (size_t)n * 128 + k] = (unsigned short)hi;
  wt[lobase + (size_t)n * 128 + k] = (unsigned short)lo;
}

// ---- aggregates over packed-bf16 rows ----
// D=128, bf16 out: rows 16 uint4; 16 lanes/row, 4 edge slots, x2 unroll.
__global__ __launch_bounds__(256) void aggregate128_bf16_kernel(
    const uint4* __restrict__ hq, const float* __restrict__ gscale,
    const float* __restrict__ wscale, const int* __restrict__ offsets,
    const int* __restrict__ csr, uint4* __restrict__ outq, int n) {
  int node = blockIdx.x * 4 + (threadIdx.x >> 6);
  if (node >= n) return;
  int lane = threadIdx.x & 63;
  int c = lane & 15;
  int p = lane >> 4;
  int s = offsets[node], e = offsets[node + 1];
  float acc[8];
#pragma unroll
  for (int j = 0; j < 8; j++) acc[j] = 0.f;
  int i = s + p;
  for (; i + 4 < e; i += 8) {
    int sn0 = csr[i], sn1 = csr[i + 4];
    uint4 u0 = hq[(size_t)sn0 * 16 + c];
    uint4 u1 = hq[(size_t)sn1 * 16 + c];
    float s0 = gscale[sn0], s1 = gscale[sn1];
    float f0[8], f1[8];
    bfunpack8(u0, f0); bfunpack8(u1, f1);
#pragma unroll
    for (int j = 0; j < 8; j++) acc[j] += f0[j] * s0 + f1[j] * s1;
  }
  if (i < e) {
    int sn = csr[i];
    uint4 u = hq[(size_t)sn * 16 + c];
    float sc = gscale[sn];
    float f[8];
    bfunpack8(u, f);
#pragma unroll
    for (int j = 0; j < 8; j++) acc[j] += f[j] * sc;
  }
#pragma unroll
  for (int off = 32; off >= 16; off >>= 1)
#pragma unroll
    for (int j = 0; j < 8; j++) acc[j] += __shfl_down(acc[j], off);
  if (lane < 16) {
    float w = wscale[node];
    uint4 q;
    q.x = bfpack(acc[0] * w, acc[1] * w); q.y = bfpack(acc[2] * w, acc[3] * w);
    q.z = bfpack(acc[4] * w, acc[5] * w); q.w = bfpack(acc[6] * w, acc[7] * w);
    outq[(size_t)node * 16 + c] = q;
  }
}

// Dual: out1(bf16) = w.*agg(g1.*h), out2(fp32 res) = w.*agg(g2.*h), one pass.
__global__ __launch_bounds__(256) void aggregate_dual_bf16_kernel(
    const uint4* __restrict__ hq, const float* __restrict__ g1,
    const float* __restrict__ g2, const float* __restrict__ wscale,
    const int* __restrict__ offsets, const int* __restrict__ csr,
    uint4* __restrict__ out1q, float* __restrict__ out2, int n) {
  int node = blockIdx.x * 4 + (threadIdx.x >> 6);
  if (node >= n) return;
  int lane = threadIdx.x & 63;
  int c = lane & 15;
  int p = lane >> 4;
  int s = offsets[node], e = offsets[node + 1];
  float a1[8], a2[8];
#pragma unroll
  for (int j = 0; j < 8; j++) { a1[j] = 0.f; a2[j] = 0.f; }
  int i = s + p;
  for (; i + 4 < e; i += 8) {
    int sn0 = csr[i], sn1 = csr[i + 4];
    uint4 u0 = hq[(size_t)sn0 * 16 + c];
    uint4 u1 = hq[(size_t)sn1 * 16 + c];
    float g1a = g1[sn0], g2a = g2[sn0];
    float g1b = g1[sn1], g2b = g2[sn1];
    float f0[8], f1[8];
    bfunpack8(u0, f0); bfunpack8(u1, f1);
#pragma unroll
    for (int j = 0; j < 8; j++) {
      a1[j] += f0[j] * g1a + f1[j] * g1b;
      a2[j] += f0[j] * g2a + f1[j] * g2b;
    }
  }
  if (i < e) {
    int sn = csr[i];
    uint4 u = hq[(size_t)sn * 16 + c];
    float g1a = g1[sn], g2a = g2[sn];
    float f[8];
    bfunpack8(u, f);
#pragma unroll
    for (int j = 0; j < 8; j++) { a1[j] += f[j] * g1a; a2[j] += f[j] * g2a; }
  }
#pragma unroll
  for (int off = 32; off >= 16; off >>= 1)
#pragma unroll
    for (int j = 0; j < 8; j++) {
      a1[j] += __shfl_down(a1[j], off);
      a2[j] += __shfl_down(a2[j], off);
    }
  if (lane < 16) {
    float w = wscale[node];
    uint4 q;
    q.x = bfpack(a1[0] * w, a1[1] * w); q.y = bfpack(a1[2] * w, a1[3] * w);
    q.z = bfpack(a1[4] * w, a1[5] * w); q.w = bfpack(a1[6] * w, a1[7] * w);
    out1q[(size_t)node * 16 + c] = q;
    float4* o2 = (float4*)(out2 + (size_t)node * 128);
    o2[2 * c]     = make_float4(a2[0] * w, a2[1] * w, a2[2] * w, a2[3] * w);
    o2[2 * c + 1] = make_float4(a2[4] * w, a2[5] * w, a2[6] * w, a2[7] * w);
  }
}

// D=64 (final, + bias, fp32 out): rows 8 uint4; 8 lanes/row, 8 slots.
__global__ __launch_bounds__(256) void aggregate64_bf16_kernel(
    const uint4* __restrict__ hq, const float* __restrict__ gscale,
    const float* __restrict__ wscale, const float* __restrict__ bias,
    const int* __restrict__ offsets, const int* __restrict__ csr,
    float* __restrict__ out, int n) {
  int node = blockIdx.x * 4 + (threadIdx.x >> 6);
  if (node >= n) return;
  int lane = threadIdx.x & 63;
  int c = lane & 7;
  int p = lane >> 3;
  int s = offsets[node], e = offsets[node + 1];
  float acc[8];
#pragma unroll
  for (int j = 0; j < 8; j++) acc[j] = 0.f;
  int i = s + p;
  for (; i + 8 < e; i += 16) {
    int sn0 = csr[i], sn1 = csr[i + 8];
    uint4 u0 = hq[(size_t)sn0 * 8 + c];
    uint4 u1 = hq[(size_t)sn1 * 8 + c];
    float s0 = gscale[sn0], s1 = gscale[sn1];
    float f0[8], f1[8];
    bfunpack8(u0, f0); bfunpack8(u1, f1);
#pragma unroll
    for (int j = 0; j < 8; j++) acc[j] += f0[j] * s0 + f1[j] * s1;
  }
  if (i < e) {
    int sn = csr[i];
    uint4 u = hq[(size_t)sn * 8 + c];
    float sc = gscale[sn];
    float f[8];
    bfunpack8(u, f);
#pragma unroll
    for (int j = 0; j < 8; j++) acc[j] += f[j] * sc;
  }
#pragma unroll
  for (int off = 32; off >= 8; off >>= 1)
#pragma unroll
    for (int j = 0; j < 8; j++) acc[j] += __shfl_down(acc[j], off);
  if (lane < 8) {
    float w = wscale[node];
    const float4* bp = (const float4*)bias;
    float4 b0 = bp[2 * c], b1 = bp[2 * c + 1];
    float4* orow = (float4*)(out + (size_t)node * 64);
    orow[2 * c]     = make_float4(acc[0] * w + b0.x, acc[1] * w + b0.y,
                                  acc[2] * w + b0.z, acc[3] * w + b0.w);
    orow[2 * c + 1] = make_float4(acc[4] * w + b1.x, acc[5] * w + b1.y,
                                  acc[6] * w + b1.z, acc[7] * w + b1.w);
  }
}

// ---- MFMA bf16 GEMM: out(M x NT*16) = A(M x 128) @ W + [bias] + [res], relu? ----
// A bf16 row-major. W given transposed [NT*16][128] as hi+lo bf16 planes.
// Per wave: 32 rows (2 row-tiles), A-frags in regs, W-frags streamed from L2.
// Fragment layout (16x16x32): A row=lane%16, k=8*(lane/16)+i ; B col=lane%16,
// same k (from W^T rows) ; D row=4*(lane/16)+reg, col=lane%16 (m89-verified).
template <int NT, bool RELU, bool HAS_BIAS, bool ADD_RES>
__global__ __launch_bounds__(256) void mfma_gemm_kernel(
    const unsigned short* __restrict__ Abf, const unsigned short* __restrict__ Wth,
    const unsigned short* __restrict__ Wtl, const float* __restrict__ bias,
    const float* __restrict__ res, unsigned short* __restrict__ outbf, int M) {
  constexpr int DOUT = NT * 16;
  int wid = threadIdx.x >> 6, lane = threadIdx.x & 63;
  int row0 = (blockIdx.x * 4 + wid) * 32;
  int lr = lane & 15, g = lane >> 4;
  bf16x8 a[2][4];
  bf16x8 zz = {0, 0, 0, 0, 0, 0, 0, 0};
#pragma unroll
  for (int rt = 0; rt < 2; rt++) {
    int r = row0 + rt * 16 + lr;
    if (r < M) {
      const unsigned short* ap = Abf + (size_t)r * 128 + g * 8;
#pragma unroll
      for (int s = 0; s < 4; s++) a[rt][s] = *(const bf16x8*)(ap + s * 32);
    } else {
#pragma unroll
      for (int s = 0; s < 4; s++) a[rt][s] = zz;
    }
  }
#pragma unroll
  for (int ct = 0; ct < NT; ct++) {
    const unsigned short* wph = Wth + (size_t)(ct * 16 + lr) * 128 + g * 8;
    const unsigned short* wpl = Wtl + (size_t)(ct * 16 + lr) * 128 + g * 8;
    bf16x8 wh[4], wl[4];
#pragma unroll
    for (int s = 0; s < 4; s++) {
      wh[s] = *(const bf16x8*)(wph + s * 32);
      wl[s] = *(const bf16x8*)(wpl + s * 32);
    }
    f32x4 acc0 = {0.f, 0.f, 0.f, 0.f}, acc1 = {0.f, 0.f, 0.f, 0.f};
#pragma unroll
    for (int s = 0; s < 4; s++) {
      acc0 = __builtin_amdgcn_mfma_f32_16x16x32_bf16(a[0][s], wh[s], acc0, 0, 0, 0);
      acc0 = __builtin_amdgcn_mfma_f32_16x16x32_bf16(a[0][s], wl[s], acc0, 0, 0, 0);
      acc1 = __builtin_amdgcn_mfma_f32_16x16x32_bf16(a[1][s], wh[s], acc1, 0, 0, 0);
      acc1 = __builtin_amdgcn_mfma_f32_16x16x32_bf16(a[1][s], wl[s], acc1, 0, 0, 0);
    }
    int col = ct * 16 + lr;
    float bv = HAS_BIAS ? bias[col] : 0.f;
#pragma unroll
    for (int rt = 0; rt < 2; rt++) {
      f32x4 acc = rt ? acc1 : acc0;
#pragma unroll
      for (int j = 0; j < 4; j++) {
        int r = row0 + rt * 16 + g * 4 + j;
        if (r < M) {
          float v = acc[j] + bv;
          if (ADD_RES) v += res[(size_t)r * 128 + col];
          if (RELU) v = fmaxf(v, 0.f);
          outbf[(size_t)r * DOUT + col] = (unsigned short)bfr(v);
        }
      }
    }
  }
}

extern "C" void kernel_launch(void* const* d_in, const int* in_sizes, int n_in,
                              void* d_out, int out_size, void* d_ws, size_t ws_size,
                              hipStream_t stream) {
  const float* features = (const float*)d_in[0];
  const int*   src      = (const int*)d_in[1];
  const int*   dst      = (const int*)d_in[2];
  const float* W0 = (const float*)d_in[3];
  const float* b0 = (const float*)d_in[4];
  const float* W1 = (const float*)d_in[5];
  const float* b1 = (const float*)d_in[6];
  const float* W2 = (const float*)d_in[7];
  const float* b2 = (const float*)d_in[8];
  const float* W3 = (const float*)d_in[9];
  const float* b3 = (const float*)d_in[10];
  float* out = (float*)d_out;
  const int N = GN, E = GE;

  char* ws = (char*)d_ws;
  size_t off = 0;
  auto alloc = [&](size_t bytes) -> void* {
    void* p = ws + off;
    off = (off + bytes + 255) & ~(size_t)255;
    return p;
  };
  unsigned int* partials = (unsigned int*)alloc((size_t)2 * 2 * DEG_BLOCKS * HALF_WORDS * 4);
  unsigned int* rel16pk  = (unsigned int*)alloc((size_t)DEG_BLOCKS * GN * 2);
  int*   indeg   = (int*)alloc((size_t)N * 4);
  float* innorm  = (float*)alloc((size_t)N * 4);
  float* outnorm = (float*)alloc((size_t)N * 4);
  int*   offsets = (int*)alloc((size_t)(N + 1) * 4);
  int*   csr     = (int*)alloc((size_t)E * 4);
  int*   bsums   = (int*)alloc((size_t)256 * 4);
  int*   bpref   = (int*)alloc((size_t)256 * 4);
  unsigned short* wt = (unsigned short*)alloc((size_t)114688 * 2);
  uint4* fbf = (uint4*)alloc((size_t)N * 128 * 2);       // features bf16
  float* res = (float*)alloc((size_t)N * 128 * 4);       // fp32; Ybf aliases later
  unsigned short* tbf = (unsigned short*)alloc((size_t)N * 128 * 2);  // t0/t1/t2
  unsigned short* hbf = (unsigned short*)alloc((size_t)N * 128 * 2);  // h0/h1/h2
  (void)ws_size; (void)in_sizes; (void)n_in; (void)out_size;

  unsigned short* Ybf = (unsigned short*)res;  // Y bf16 (res dead after gemm2)
  const unsigned short *w0h = wt,          *w0l = wt + 16384;
  const unsigned short *w1h = wt + 32768,  *w1l = wt + 49152;
  const unsigned short *w2h = wt + 65536,  *w2l = wt + 81920;
  const unsigned short *w3h = wt + 98304,  *w3l = wt + 106496;

  // graph prep (no global atomics anywhere)
  degrees_lds_kernel<<<256, 256, 0, stream>>>(src, dst, partials, E);
  degrees_reduce_kernel<<<(2 * HALF_WORDS + 255) / 256, 256, 0, stream>>>(
      partials, indeg, innorm, outnorm, rel16pk);

  int nb = (N + SCAN_CHUNK - 1) / SCAN_CHUNK;  // 49
  scan_blocksums<<<nb, 256, 0, stream>>>(indeg, bsums, N);
  scan_bsums<<<1, 64, 0, stream>>>(bsums, bpref, nb, offsets, N);
  scan_final<<<nb, 256, 0, stream>>>(indeg, bpref, offsets, N);

  fill_csr_lds_kernel<<<128, 256, 0, stream>>>(
      src, dst, offsets, (const unsigned short*)rel16pk, csr, E);

  wconvert_kernel<<<(57344 + 255) / 256, 256, 0, stream>>>(W0, W1, W2, W3, wt);
  f32_to_bf16_kernel<<<(N * 128 / 8 + 255) / 256, 256, 0, stream>>>(
      features, fbf, N * 128 / 8);

  int aggGrid  = (N + 3) / 4;
  int gemmGrid = (N + 127) / 128;  // 4 waves x 32 rows per block

  // t0(bf16) = innorm.*agg(outnorm.*f); res(fp32) = innorm.*agg(innorm.*f)
  aggregate_dual_bf16_kernel<<<aggGrid, 256, 0, stream>>>(
      fbf, outnorm, innorm, innorm, offsets, csr, (uint4*)tbf, res, N);
  // h0 = relu(t0 @ W0 + b0) -> bf16
  mfma_gemm_kernel<8, true, true, false><<<gemmGrid, 256, 0, stream>>>(
      tbf, w0h, w0l, b0, nullptr, hbf, N);
  // t1 = innorm .* agg(outnorm .* h0) -> bf16
  aggregate128_bf16_kernel<<<aggGrid, 256, 0, stream>>>(
      (const uint4*)hbf, outnorm, innorm, offsets, csr, (uint4*)tbf, N);
  // h1 = relu(t1 @ W1 + b1 + res) -> bf16
  mfma_gemm_kernel<8, true, true, true><<<gemmGrid, 256, 0, stream>>>(
      tbf, w1h, w1l, b1, res, hbf, N);
  // t2 = innorm .* agg(outnorm .* h1) -> bf16
  aggregate128_bf16_kernel<<<aggGrid, 256, 0, stream>>>(
      (const uint4*)hbf, outnorm, innorm, offsets, csr, (uint4*)tbf, N);
  // h2 = relu(t2 @ W2 + b2 + res) -> bf16
  mfma_gemm_kernel<8, true, true, true><<<gemmGrid, 256, 0, stream>>>(
      tbf, w2h, w2l, b2, res, hbf, N);
  // Y = h2 @ W3 -> bf16 (res dead; Ybf aliases it)
  mfma_gemm_kernel<4, false, false, false><<<gemmGrid, 256, 0, stream>>>(
      hbf, w3h, w3l, nullptr, nullptr, Ybf, N);
  // out = innorm .* agg(outnorm .* Y) + b3
  aggregate64_bf16_kernel<<<aggGrid, 256, 0, stream>>>(
      (const uint4*)Ybf, outnorm, innorm, b3, offsets, csr, out, N);
}

// Round 7
// 363.647 us; speedup vs baseline: 1.9648x; 1.0594x over previous
//
#include <hip/hip_runtime.h>

// GResNet GCN: N=50000, E=800000, d=128 (out 64).
// R7 changes:
//  (1) 4-deep gather pipeline in dual/128 aggregates (16 row-loads in flight).
//  (2) packed float2 norms (one 8B random load per edge in dual, not two 4B).
//  (3) res stored bf16 (halves its write + 2 GEMM-epilogue reads).
//  (4) degrees/fill blocks at 512 threads (halve serial iters).

#define GN 50000
#define GE 800000
#define SCAN_CHUNK 1024
#define DEG_BLOCKS 64
#define DEG_SLICE 12500      // GE / DEG_BLOCKS
#define HALF_NODES 25000
#define HALF_WORDS 12500     // packed uint16 pairs

typedef __attribute__((ext_vector_type(8))) short bf16x8;
typedef __attribute__((ext_vector_type(4))) float f32x4;

__device__ __forceinline__ float u2f(unsigned int u) { return __uint_as_float(u); }

__device__ __forceinline__ unsigned int bfr(float a) {   // fp32 -> bf16 bits (RNE)
  unsigned int u = __float_as_uint(a);
  return (u + 0x7fffu + ((u >> 16) & 1u)) >> 16;
}
__device__ __forceinline__ unsigned int bfpack(float a, float b) {
  return bfr(a) | (bfr(b) << 16);
}
__device__ __forceinline__ void bfunpack8(uint4 u, float* f) {
  f[0] = u2f(u.x << 16); f[1] = u2f(u.x & 0xffff0000u);
  f[2] = u2f(u.y << 16); f[3] = u2f(u.y & 0xffff0000u);
  f[4] = u2f(u.z << 16); f[5] = u2f(u.z & 0xffff0000u);
  f[6] = u2f(u.w << 16); f[7] = u2f(u.w & 0xffff0000u);
}

// ---- degrees via LDS histograms ----
__global__ __launch_bounds__(512) void degrees_lds_kernel(
    const int* __restrict__ src, const int* __restrict__ dst,
    unsigned int* __restrict__ partials, int E) {
  __shared__ unsigned int hist[HALF_WORDS];
  for (int i = threadIdx.x; i < HALF_WORDS; i += 512) hist[i] = 0u;
  __syncthreads();
  int b    = blockIdx.x & 63;
  int half = (blockIdx.x >> 6) & 1;
  int dir  = blockIdx.x >> 7;
  const int* __restrict__ idx = dir ? src : dst;
  int lo = half * HALF_NODES, hi = lo + HALF_NODES;
  int s = b * DEG_SLICE;
  int e = min(s + DEG_SLICE, E);
  for (int i = s + threadIdx.x; i < e; i += 512) {
    int node = idx[i];
    if (node >= lo && node < hi) {
      int local = node - lo;
      atomicAdd(&hist[local >> 1], 1u << ((local & 1) << 4));
    }
  }
  __syncthreads();
  unsigned int* outp = partials + (((size_t)dir * 2 + half) * DEG_BLOCKS + b) * HALF_WORDS;
  for (int i = threadIdx.x; i < HALF_WORDS; i += 512) outp[i] = hist[i];
}

// Reduce partials -> indeg/norms (+ packed float2 norms), rel16 slice prefix.
__global__ void degrees_reduce_kernel(const unsigned int* __restrict__ partials,
                                      int* __restrict__ indeg, float* __restrict__ innorm,
                                      float* __restrict__ outnorm, float2* __restrict__ nrm2,
                                      unsigned int* __restrict__ rel16pk) {
  int g = blockIdx.x * blockDim.x + threadIdx.x;
  if (g >= 2 * HALF_WORDS) return;
  int half = (g >= HALF_WORDS) ? 1 : 0;
  int w = g - half * HALF_WORDS;
  int n0 = half * HALF_NODES + 2 * w;
  unsigned int inLo = 0, inHi = 0, outLo = 0, outHi = 0;
  const unsigned int* pIn  = partials + ((size_t)(0 * 2 + half) * DEG_BLOCKS) * HALF_WORDS + w;
  const unsigned int* pOut = partials + ((size_t)(1 * 2 + half) * DEG_BLOCKS) * HALF_WORDS + w;
#pragma unroll 4
  for (int b = 0; b < DEG_BLOCKS; b++) {
    rel16pk[((size_t)b * GN + n0) >> 1] = inLo | (inHi << 16);
    unsigned int v = pIn[(size_t)b * HALF_WORDS];
    inLo += v & 0xffffu; inHi += v >> 16;
    unsigned int u = pOut[(size_t)b * HALF_WORDS];
    outLo += u & 0xffffu; outHi += u >> 16;
  }
  indeg[n0]     = (int)inLo;
  indeg[n0 + 1] = (int)inHi;
  float i0 = rsqrtf((float)max((int)inLo, 1)),  i1 = rsqrtf((float)max((int)inHi, 1));
  float o0 = rsqrtf((float)max((int)outLo, 1)), o1 = rsqrtf((float)max((int)outHi, 1));
  innorm[n0] = i0; innorm[n0 + 1] = i1;
  outnorm[n0] = o0; outnorm[n0 + 1] = o1;
  nrm2[n0]     = make_float2(o0, i0);
  nrm2[n0 + 1] = make_float2(o1, i1);
}

// ---- hierarchical scan over indeg -> offsets ----
__global__ __launch_bounds__(256) void scan_blocksums(const int* __restrict__ deg,
                                                      int* __restrict__ bsums, int n) {
  int tid = threadIdx.x;
  int i = blockIdx.x * SCAN_CHUNK + tid * 4;
  int s = 0;
  if (i + 3 < n) {
    int4 v = *(const int4*)(deg + i);
    s = v.x + v.y + v.z + v.w;
  } else {
    for (int j = 0; j < 4; j++) if (i + j < n) s += deg[i + j];
  }
  for (int off = 32; off; off >>= 1) s += __shfl_down(s, off);
  __shared__ int ws[4];
  if ((tid & 63) == 0) ws[tid >> 6] = s;
  __syncthreads();
  if (tid == 0) bsums[blockIdx.x] = ws[0] + ws[1] + ws[2] + ws[3];
}

__global__ void scan_bsums(const int* __restrict__ bsums, int* __restrict__ bpref,
                           int nb, int* __restrict__ offsets, int n) {
  int tid = threadIdx.x;
  int v = (tid < nb) ? bsums[tid] : 0;
  int incl = v;
  for (int off = 1; off < 64; off <<= 1) {
    int t = __shfl_up(incl, off);
    if (tid >= off) incl += t;
  }
  if (tid < nb) bpref[tid] = incl - v;
  if (tid == 63) offsets[n] = incl;
}

__global__ __launch_bounds__(256) void scan_final(const int* __restrict__ deg,
                                                  const int* __restrict__ bpref,
                                                  int* __restrict__ offsets, int n) {
  int tid = threadIdx.x;
  int i = blockIdx.x * SCAN_CHUNK + tid * 4;
  int v[4];
#pragma unroll
  for (int j = 0; j < 4; j++) v[j] = (i + j < n) ? deg[i + j] : 0;
  int tsum = v[0] + v[1] + v[2] + v[3];
  int incl = tsum;
  for (int off = 1; off < 64; off <<= 1) {
    int t = __shfl_up(incl, off);
    if ((tid & 63) >= off) incl += t;
  }
  __shared__ int wsum[4];
  int wid = tid >> 6, lane = tid & 63;
  if (lane == 63) wsum[wid] = incl;
  __syncthreads();
  int wpref = 0;
  for (int w = 0; w < wid; w++) wpref += wsum[w];
  int run = bpref[blockIdx.x] + wpref + incl - tsum;
#pragma unroll
  for (int j = 0; j < 4; j++) {
    if (i + j < n) offsets[i + j] = run;
    run += v[j];
  }
}

// ---- CSR fill via LDS counting sort ----
__global__ __launch_bounds__(512) void fill_csr_lds_kernel(
    const int* __restrict__ src, const int* __restrict__ dst,
    const int* __restrict__ offsets, const unsigned short* __restrict__ rel16,
    int* __restrict__ csr, int E) {
  __shared__ unsigned int cnt[HALF_WORDS];
  for (int i = threadIdx.x; i < HALF_WORDS; i += 512) cnt[i] = 0u;
  __syncthreads();
  int b    = blockIdx.x & 63;
  int half = blockIdx.x >> 6;
  int lo = half * HALF_NODES, hi = lo + HALF_NODES;
  int s = b * DEG_SLICE;
  int e = min(s + DEG_SLICE, E);
  const unsigned short* relb = rel16 + (size_t)b * GN;
  for (int i = s + threadIdx.x; i < e; i += 512) {
    int d = dst[i];
    if (d >= lo && d < hi) {
      int local = d - lo;
      int sh = (local & 1) << 4;
      unsigned int old = atomicAdd(&cnt[local >> 1], 1u << sh);
      int rank = (int)((old >> sh) & 0xffffu);
      int pos = offsets[d] + (int)relb[d] + rank;
      csr[pos] = src[i];
    }
  }
}

// ---- feature fp32 -> packed bf16 ----
__global__ __launch_bounds__(256) void f32_to_bf16_kernel(const float* __restrict__ in,
                                                          uint4* __restrict__ out, int n8) {
  int t = blockIdx.x * blockDim.x + threadIdx.x;
  if (t >= n8) return;
  const float4* in4 = (const float4*)in;
  float4 f0 = in4[2 * t], f1 = in4[2 * t + 1];
  uint4 o;
  o.x = bfpack(f0.x, f0.y); o.y = bfpack(f0.z, f0.w);
  o.z = bfpack(f1.x, f1.y); o.w = bfpack(f1.z, f1.w);
  out[t] = o;
}

// ---- W -> transposed bf16 hi/lo planes ----
__global__ __launch_bounds__(256) void wconvert_kernel(
    const float* __restrict__ W0, const float* __restrict__ W1,
    const float* __restrict__ W2, const float* __restrict__ W3,
    unsigned short* __restrict__ wt) {
  int e = blockIdx.x * 256 + threadIdx.x;
  if (e >= 3 * 16384 + 8192) return;
  int m, local, N;
  if (e < 49152) { m = e >> 14; local = e & 16383; N = 128; }
  else { m = 3; local = e - 49152; N = 64; }
  const float* W = (m == 0) ? W0 : (m == 1) ? W1 : (m == 2) ? W2 : W3;
  int k = local / N, n = local % N;
  float v = W[k * N + n];
  unsigned int hi = bfr(v);
  float rem = v - u2f(hi << 16);
  unsigned int lo = bfr(rem);
  size_t hibase = (m < 3) ? (size_t)m * 32768 : 98304;
  size_t lobase = hibase + ((m < 3) ? 16384 : 8192);
  wt[hibase + (size_t)n * 128 + k] = (unsigned short)hi;
  wt[lobase + (size_t)n * 128 + k] = (unsigned short)lo;
}

// ---- aggregates over packed-bf16 rows ----
// D=128, bf16 out: 16 lanes/row, 4 edge slots, 4-deep pipeline.
__global__ __launch_bounds__(256) void aggregate128_bf16_kernel(
    const uint4* __restrict__ hq, const float* __restrict__ gscale,
    const float* __restrict__ wscale, const int* __restrict__ offsets,
    const int* __restrict__ csr, uint4* __restrict__ outq, int n) {
  int node = blockIdx.x * 4 + (threadIdx.x >> 6);
  if (node >= n) return;
  int lane = threadIdx.x & 63;
  int c = lane & 15;
  int p = lane >> 4;
  int s = offsets[node], e = offsets[node + 1];
  float acc[8];
#pragma unroll
  for (int j = 0; j < 8; j++) acc[j] = 0.f;
  int i = s + p;
  for (; i + 12 < e; i += 16) {
    int sn[4];
#pragma unroll
    for (int q = 0; q < 4; q++) sn[q] = csr[i + 4 * q];
    uint4 u[4]; float sv[4];
#pragma unroll
    for (int q = 0; q < 4; q++) {
      u[q] = hq[(size_t)sn[q] * 16 + c];
      sv[q] = gscale[sn[q]];
    }
#pragma unroll
    for (int q = 0; q < 4; q++) {
      float f[8]; bfunpack8(u[q], f);
#pragma unroll
      for (int j = 0; j < 8; j++) acc[j] += f[j] * sv[q];
    }
  }
  for (; i + 4 < e; i += 8) {
    int sn0 = csr[i], sn1 = csr[i + 4];
    uint4 u0 = hq[(size_t)sn0 * 16 + c];
    uint4 u1 = hq[(size_t)sn1 * 16 + c];
    float s0 = gscale[sn0], s1 = gscale[sn1];
    float f0[8], f1[8];
    bfunpack8(u0, f0); bfunpack8(u1, f1);
#pragma unroll
    for (int j = 0; j < 8; j++) acc[j] += f0[j] * s0 + f1[j] * s1;
  }
  if (i < e) {
    int sn = csr[i];
    uint4 u = hq[(size_t)sn * 16 + c];
    float sc = gscale[sn];
    float f[8]; bfunpack8(u, f);
#pragma unroll
    for (int j = 0; j < 8; j++) acc[j] += f[j] * sc;
  }
#pragma unroll
  for (int off = 32; off >= 16; off >>= 1)
#pragma unroll
    for (int j = 0; j < 8; j++) acc[j] += __shfl_down(acc[j], off);
  if (lane < 16) {
    float w = wscale[node];
    uint4 q;
    q.x = bfpack(acc[0] * w, acc[1] * w); q.y = bfpack(acc[2] * w, acc[3] * w);
    q.z = bfpack(acc[4] * w, acc[5] * w); q.w = bfpack(acc[6] * w, acc[7] * w);
    outq[(size_t)node * 16 + c] = q;
  }
}

// Dual: out1(bf16) = in.*agg(out.*h), out2(bf16 res) = in.*agg(in.*h), one pass.
// nrm2[sn] = (outnorm, innorm) -- one 8B random load per edge.
__global__ __launch_bounds__(256) void aggregate_dual_bf16_kernel(
    const uint4* __restrict__ hq, const float2* __restrict__ nrm2,
    const float* __restrict__ wscale, const int* __restrict__ offsets,
    const int* __restrict__ csr, uint4* __restrict__ out1q,
    uint4* __restrict__ out2q, int n) {
  int node = blockIdx.x * 4 + (threadIdx.x >> 6);
  if (node >= n) return;
  int lane = threadIdx.x & 63;
  int c = lane & 15;
  int p = lane >> 4;
  int s = offsets[node], e = offsets[node + 1];
  float a1[8], a2[8];
#pragma unroll
  for (int j = 0; j < 8; j++) { a1[j] = 0.f; a2[j] = 0.f; }
  int i = s + p;
  for (; i + 12 < e; i += 16) {
    int sn[4];
#pragma unroll
    for (int q = 0; q < 4; q++) sn[q] = csr[i + 4 * q];
    uint4 u[4]; float2 g[4];
#pragma unroll
    for (int q = 0; q < 4; q++) {
      u[q] = hq[(size_t)sn[q] * 16 + c];
      g[q] = nrm2[sn[q]];
    }
#pragma unroll
    for (int q = 0; q < 4; q++) {
      float f[8]; bfunpack8(u[q], f);
#pragma unroll
      for (int j = 0; j < 8; j++) {
        a1[j] += f[j] * g[q].x;
        a2[j] += f[j] * g[q].y;
      }
    }
  }
  for (; i + 4 < e; i += 8) {
    int sn0 = csr[i], sn1 = csr[i + 4];
    uint4 u0 = hq[(size_t)sn0 * 16 + c];
    uint4 u1 = hq[(size_t)sn1 * 16 + c];
    float2 ga = nrm2[sn0], gb = nrm2[sn1];
    float f0[8], f1[8];
    bfunpack8(u0, f0); bfunpack8(u1, f1);
#pragma unroll
    for (int j = 0; j < 8; j++) {
      a1[j] += f0[j] * ga.x + f1[j] * gb.x;
      a2[j] += f0[j] * ga.y + f1[j] * gb.y;
    }
  }
  if (i < e) {
    int sn = csr[i];
    uint4 u = hq[(size_t)sn * 16 + c];
    float2 ga = nrm2[sn];
    float f[8]; bfunpack8(u, f);
#pragma unroll
    for (int j = 0; j < 8; j++) { a1[j] += f[j] * ga.x; a2[j] += f[j] * ga.y; }
  }
#pragma unroll
  for (int off = 32; off >= 16; off >>= 1)
#pragma unroll
    for (int j = 0; j < 8; j++) {
      a1[j] += __shfl_down(a1[j], off);
      a2[j] += __shfl_down(a2[j], off);
    }
  if (lane < 16) {
    float w = wscale[node];
    uint4 q1, q2;
    q1.x = bfpack(a1[0] * w, a1[1] * w); q1.y = bfpack(a1[2] * w, a1[3] * w);
    q1.z = bfpack(a1[4] * w, a1[5] * w); q1.w = bfpack(a1[6] * w, a1[7] * w);
    q2.x = bfpack(a2[0] * w, a2[1] * w); q2.y = bfpack(a2[2] * w, a2[3] * w);
    q2.z = bfpack(a2[4] * w, a2[5] * w); q2.w = bfpack(a2[6] * w, a2[7] * w);
    out1q[(size_t)node * 16 + c] = q1;
    out2q[(size_t)node * 16 + c] = q2;
  }
}

// D=64 (final, + bias, fp32 out): 8 lanes/row, 8 slots, 2-deep.
__global__ __launch_bounds__(256) void aggregate64_bf16_kernel(
    const uint4* __restrict__ hq, const float* __restrict__ gscale,
    const float* __restrict__ wscale, const float* __restrict__ bias,
    const int* __restrict__ offsets, const int* __restrict__ csr,
    float* __restrict__ out, int n) {
  int node = blockIdx.x * 4 + (threadIdx.x >> 6);
  if (node >= n) return;
  int lane = threadIdx.x & 63;
  int c = lane & 7;
  int p = lane >> 3;
  int s = offsets[node], e = offsets[node + 1];
  float acc[8];
#pragma unroll
  for (int j = 0; j < 8; j++) acc[j] = 0.f;
  int i = s + p;
  for (; i + 8 < e; i += 16) {
    int sn0 = csr[i], sn1 = csr[i + 8];
    uint4 u0 = hq[(size_t)sn0 * 8 + c];
    uint4 u1 = hq[(size_t)sn1 * 8 + c];
    float s0 = gscale[sn0], s1 = gscale[sn1];
    float f0[8], f1[8];
    bfunpack8(u0, f0); bfunpack8(u1, f1);
#pragma unroll
    for (int j = 0; j < 8; j++) acc[j] += f0[j] * s0 + f1[j] * s1;
  }
  if (i < e) {
    int sn = csr[i];
    uint4 u = hq[(size_t)sn * 8 + c];
    float sc = gscale[sn];
    float f[8]; bfunpack8(u, f);
#pragma unroll
    for (int j = 0; j < 8; j++) acc[j] += f[j] * sc;
  }
#pragma unroll
  for (int off = 32; off >= 8; off >>= 1)
#pragma unroll
    for (int j = 0; j < 8; j++) acc[j] += __shfl_down(acc[j], off);
  if (lane < 8) {
    float w = wscale[node];
    const float4* bp = (const float4*)bias;
    float4 b0 = bp[2 * c], b1 = bp[2 * c + 1];
    float4* orow = (float4*)(out + (size_t)node * 64);
    orow[2 * c]     = make_float4(acc[0] * w + b0.x, acc[1] * w + b0.y,
                                  acc[2] * w + b0.z, acc[3] * w + b0.w);
    orow[2 * c + 1] = make_float4(acc[4] * w + b1.x, acc[5] * w + b1.y,
                                  acc[6] * w + b1.z, acc[7] * w + b1.w);
  }
}

// ---- MFMA bf16 GEMM: out = A(Mx128) @ W + [bias] + [res bf16], relu? ----
template <int NT, bool RELU, bool HAS_BIAS, bool ADD_RES>
__global__ __launch_bounds__(256) void mfma_gemm_kernel(
    const unsigned short* __restrict__ Abf, const unsigned short* __restrict__ Wth,
    const unsigned short* __restrict__ Wtl, const float* __restrict__ bias,
    const unsigned short* __restrict__ resbf, unsigned short* __restrict__ outbf, int M) {
  constexpr int DOUT = NT * 16;
  int wid = threadIdx.x >> 6, lane = threadIdx.x & 63;
  int row0 = (blockIdx.x * 4 + wid) * 32;
  int lr = lane & 15, g = lane >> 4;
  bf16x8 a[2][4];
  bf16x8 zz = {0, 0, 0, 0, 0, 0, 0, 0};
#pragma unroll
  for (int rt = 0; rt < 2; rt++) {
    int r = row0 + rt * 16 + lr;
    if (r < M) {
      const unsigned short* ap = Abf + (size_t)r * 128 + g * 8;
#pragma unroll
      for (int s = 0; s < 4; s++) a[rt][s] = *(const bf16x8*)(ap + s * 32);
    } else {
#pragma unroll
      for (int s = 0; s < 4; s++) a[rt][s] = zz;
    }
  }
#pragma unroll
  for (int ct = 0; ct < NT; ct++) {
    const unsigned short* wph = Wth + (size_t)(ct * 16 + lr) * 128 + g * 8;
    const unsigned short* wpl = Wtl + (size_t)(ct * 16 + lr) * 128 + g * 8;
    bf16x8 wh[4], wl[4];
#pragma unroll
    for (int s = 0; s < 4; s++) {
      wh[s] = *(const bf16x8*)(wph + s * 32);
      wl[s] = *(const bf16x8*)(wpl + s * 32);
    }
    f32x4 acc0 = {0.f, 0.f, 0.f, 0.f}, acc1 = {0.f, 0.f, 0.f, 0.f};
#pragma unroll
    for (int s = 0; s < 4; s++) {
      acc0 = __builtin_amdgcn_mfma_f32_16x16x32_bf16(a[0][s], wh[s], acc0, 0, 0, 0);
      acc0 = __builtin_amdgcn_mfma_f32_16x16x32_bf16(a[0][s], wl[s], acc0, 0, 0, 0);
      acc1 = __builtin_amdgcn_mfma_f32_16x16x32_bf16(a[1][s], wh[s], acc1, 0, 0, 0);
      acc1 = __builtin_amdgcn_mfma_f32_16x16x32_bf16(a[1][s], wl[s], acc1, 0, 0, 0);
    }
    int col = ct * 16 + lr;
    float bv = HAS_BIAS ? bias[col] : 0.f;
#pragma unroll
    for (int rt = 0; rt < 2; rt++) {
      f32x4 acc = rt ? acc1 : acc0;
#pragma unroll
      for (int j = 0; j < 4; j++) {
        int r = row0 + rt * 16 + g * 4 + j;
        if (r < M) {
          float v = acc[j] + bv;
          if (ADD_RES) v += u2f((unsigned int)resbf[(size_t)r * 128 + col] << 16);
          if (RELU) v = fmaxf(v, 0.f);
          outbf[(size_t)r * DOUT + col] = (unsigned short)bfr(v);
        }
      }
    }
  }
}

extern "C" void kernel_launch(void* const* d_in, const int* in_sizes, int n_in,
                              void* d_out, int out_size, void* d_ws, size_t ws_size,
                              hipStream_t stream) {
  const float* features = (const float*)d_in[0];
  const int*   src      = (const int*)d_in[1];
  const int*   dst      = (const int*)d_in[2];
  const float* W0 = (const float*)d_in[3];
  const float* b0 = (const float*)d_in[4];
  const float* W1 = (const float*)d_in[5];
  const float* b1 = (const float*)d_in[6];
  const float* W2 = (const float*)d_in[7];
  const float* b2 = (const float*)d_in[8];
  const float* W3 = (const float*)d_in[9];
  const float* b3 = (const float*)d_in[10];
  float* out = (float*)d_out;
  const int N = GN, E = GE;

  char* ws = (char*)d_ws;
  size_t off = 0;
  auto alloc = [&](size_t bytes) -> void* {
    void* p = ws + off;
    off = (off + bytes + 255) & ~(size_t)255;
    return p;
  };
  unsigned int* partials = (unsigned int*)alloc((size_t)2 * 2 * DEG_BLOCKS * HALF_WORDS * 4);
  unsigned int* rel16pk  = (unsigned int*)alloc((size_t)DEG_BLOCKS * GN * 2);
  int*   indeg   = (int*)alloc((size_t)N * 4);
  float* innorm  = (float*)alloc((size_t)N * 4);
  float* outnorm = (float*)alloc((size_t)N * 4);
  float2* nrm2   = (float2*)alloc((size_t)N * 8);
  int*   offsets = (int*)alloc((size_t)(N + 1) * 4);
  int*   csr     = (int*)alloc((size_t)E * 4);
  int*   bsums   = (int*)alloc((size_t)256 * 4);
  int*   bpref   = (int*)alloc((size_t)256 * 4);
  unsigned short* wt = (unsigned short*)alloc((size_t)114688 * 2);
  uint4* fbf = (uint4*)alloc((size_t)N * 128 * 2);                    // features bf16
  unsigned short* resbf = (unsigned short*)alloc((size_t)N * 128 * 2); // res bf16; Ybf aliases
  unsigned short* tbf = (unsigned short*)alloc((size_t)N * 128 * 2);  // t0/t1/t2
  unsigned short* hbf = (unsigned short*)alloc((size_t)N * 128 * 2);  // h0/h1/h2
  (void)ws_size; (void)in_sizes; (void)n_in; (void)out_size;

  unsigned short* Ybf = resbf;  // Y bf16 (res dead after h2 GEMM)
  const unsigned short *w0h = wt,          *w0l = wt + 16384;
  const unsigned short *w1h = wt + 32768,  *w1l = wt + 49152;
  const unsigned short *w2h = wt + 65536,  *w2l = wt + 81920;
  const unsigned short *w3h = wt + 98304,  *w3l = wt + 106496;

  // graph prep (no global atomics anywhere)
  degrees_lds_kernel<<<256, 512, 0, stream>>>(src, dst, partials, E);
  degrees_reduce_kernel<<<(2 * HALF_WORDS + 255) / 256, 256, 0, stream>>>(
      partials, indeg, innorm, outnorm, nrm2, rel16pk);

  int nb = (N + SCAN_CHUNK - 1) / SCAN_CHUNK;  // 49
  scan_blocksums<<<nb, 256, 0, stream>>>(indeg, bsums, N);
  scan_bsums<<<1, 64, 0, stream>>>(bsums, bpref, nb, offsets, N);
  scan_final<<<nb, 256, 0, stream>>>(indeg, bpref, offsets, N);

  fill_csr_lds_kernel<<<128, 512, 0, stream>>>(
      src, dst, offsets, (const unsigned short*)rel16pk, csr, E);

  wconvert_kernel<<<(57344 + 255) / 256, 256, 0, stream>>>(W0, W1, W2, W3, wt);
  f32_to_bf16_kernel<<<(N * 128 / 8 + 255) / 256, 256, 0, stream>>>(
      features, fbf, N * 128 / 8);

  int aggGrid  = (N + 3) / 4;
  int gemmGrid = (N + 127) / 128;  // 4 waves x 32 rows per block

  // t0(bf16) = in.*agg(out.*f); res(bf16) = in.*agg(in.*f) — one gather pass
  aggregate_dual_bf16_kernel<<<aggGrid, 256, 0, stream>>>(
      fbf, nrm2, innorm, offsets, csr, (uint4*)tbf, (uint4*)resbf, N);
  // h0 = relu(t0 @ W0 + b0) -> bf16
  mfma_gemm_kernel<8, true, true, false><<<gemmGrid, 256, 0, stream>>>(
      tbf, w0h, w0l, b0, nullptr, hbf, N);
  // t1 = in .* agg(out .* h0) -> bf16
  aggregate128_bf16_kernel<<<aggGrid, 256, 0, stream>>>(
      (const uint4*)hbf, outnorm, innorm, offsets, csr, (uint4*)tbf, N);
  // h1 = relu(t1 @ W1 + b1 + res) -> bf16
  mfma_gemm_kernel<8, true, true, true><<<gemmGrid, 256, 0, stream>>>(
      tbf, w1h, w1l, b1, resbf, hbf, N);
  // t2 = in .* agg(out .* h1) -> bf16
  aggregate128_bf16_kernel<<<aggGrid, 256, 0, stream>>>(
      (const uint4*)hbf, outnorm, innorm, offsets, csr, (uint4*)tbf, N);
  // h2 = relu(t2 @ W2 + b2 + res) -> bf16
  mfma_gemm_kernel<8, true, true, true><<<gemmGrid, 256, 0, stream>>>(
      tbf, w2h, w2l, b2, resbf, hbf, N);
  // Y = h2 @ W3 -> bf16 (res dead; Ybf aliases it)
  mfma_gemm_kernel<4, false, false, false><<<gemmGrid, 256, 0, stream>>>(
      hbf, w3h, w3l, nullptr, nullptr, Ybf, N);
  // out = in .* agg(out .* Y) + b3
  aggregate64_bf16_kernel<<<aggGrid, 256, 0, stream>>>(
      (const uint4*)Ybf, outnorm, innorm, b3, offsets, csr, out, N);
}